// Round 2
// baseline (13073.116 us; speedup 1.0000x reference)
//
#include <hip/hip_runtime.h>
#include <hip/hip_bf16.h>
#include <hip/hip_cooperative_groups.h>

namespace cg = cooperative_groups;

typedef __bf16 bf16x8 __attribute__((ext_vector_type(8)));
typedef unsigned short u16x8 __attribute__((ext_vector_type(8)));
typedef float f32x4 __attribute__((ext_vector_type(4)));

constexpr int TT = 64;   // timesteps
constexpr int BB = 64;   // batch
constexpr int SS = 128;  // memory length
constexpr int HH = 512;  // hidden
constexpr int EE = 512;  // embed
constexpr int GG = 2048; // 4*H

// hi/lo split offsets (elements)
constexpr int NW0 = 2048 * 1536;
constexpr int NW1 = 2048 * 512;
constexpr int NWO = 512 * 1024;
constexpr int NWI = 512 * 512;

struct P {
  const int* tok; const float* mbank; const int* len;
  const float* h0_in; const float* c0_in; const float* emb;
  const float* w_ih0; const float* w_hh0; const float* b_ih0; const float* b_hh0;
  const float* w_ih1; const float* w_hh1; const float* b_ih1; const float* b_hh1;
  const float* w_in; const float* w_out;
  float* out_dec; float* out_attn; float* out_hf; float* out_cf;
  unsigned short *W0, *Wih1, *Whh1, *Wout, *WinT;   // each: [hi | lo]
  float *Mw;
  float *b0, *b1, *h0buf, *h1s, *c0s, *c1s, *feed, *part1, *ctx;
};

__device__ __forceinline__ unsigned short f2bf(float f) {
  unsigned int u = __builtin_bit_cast(unsigned int, f);
  return (unsigned short)((u + 0x7fffu + ((u >> 16) & 1u)) >> 16);
}
__device__ __forceinline__ float bf2f(unsigned short h) {
  return __builtin_bit_cast(float, ((unsigned int)h) << 16);
}
__device__ __forceinline__ bf16x8 ldb(const unsigned short* p) {
  return __builtin_bit_cast(bf16x8, *(const u16x8*)p);
}
__device__ __forceinline__ f32x4 mfma_(bf16x8 a, bf16x8 b, f32x4 c) {
  return __builtin_amdgcn_mfma_f32_16x16x32_bf16(a, b, c, 0, 0, 0);
}
__device__ __forceinline__ float sigm(float x) { return 1.f / (1.f + __expf(-x)); }
__device__ __forceinline__ f32x4 zero4() { f32x4 z = {0.f, 0.f, 0.f, 0.f}; return z; }

// split 8 consecutive f32 into bf16 hi + bf16 residual lo
__device__ __forceinline__ void splitA(const float* s, bf16x8& hi, bf16x8& lo) {
  float4 a0 = *(const float4*)s;
  float4 a1 = *(const float4*)(s + 4);
  float v[8] = {a0.x, a0.y, a0.z, a0.w, a1.x, a1.y, a1.z, a1.w};
  u16x8 h, l;
#pragma unroll
  for (int j = 0; j < 8; ++j) {
    unsigned short hb = f2bf(v[j]);
    h[j] = hb;
    l[j] = f2bf(v[j] - bf2f(hb));
  }
  hi = __builtin_bit_cast(bf16x8, h);
  lo = __builtin_bit_cast(bf16x8, l);
}
// acc += A*B with split operands (3-term compensated mfma)
__device__ __forceinline__ f32x4 mfma3(bf16x8 ah, bf16x8 al, bf16x8 bh, bf16x8 bl, f32x4 c) {
  c = mfma_(al, bh, c);
  c = mfma_(ah, bl, c);
  c = mfma_(ah, bh, c);
  return c;
}

// ---------------- prep: weight split / transpose / state init ----------------
__global__ void prep_weights(P p) {
  constexpr int TOT = NW0 + NW1 + NW1 + NWO + NWI + 2048 + 2048 + 32768 * 5;
  for (int i = blockIdx.x * blockDim.x + threadIdx.x; i < TOT;
       i += gridDim.x * blockDim.x) {
    int j = i;
    float v; unsigned short* dst; int N;
    if (j < NW0) {               // W0 = [w_ih0 | w_hh0] : [2048][1536]
      int n = j / 1536, k = j - n * 1536;
      v = (k < 1024) ? p.w_ih0[n * 1024 + k] : p.w_hh0[n * 512 + (k - 1024)];
      dst = p.W0; N = NW0;
      goto split;
    }
    j -= NW0;
    if (j < NW1) { v = p.w_ih1[j]; dst = p.Wih1; N = NW1; goto split; }
    j -= NW1;
    if (j < NW1) { v = p.w_hh1[j]; dst = p.Whh1; N = NW1; goto split; }
    j -= NW1;
    if (j < NWO) { v = p.w_out[j]; dst = p.Wout; N = NWO; goto split; }
    j -= NWO;
    if (j < NWI) {               // WinT[n][k] = w_in[k][n]
      int n = j >> 9, q = j & 511;
      v = p.w_in[q * 512 + n];
      dst = p.WinT; N = NWI;
      goto split;
    }
    j -= NWI;
    if (j < 2048) { p.b0[j] = p.b_ih0[j] + p.b_hh0[j]; continue; }
    j -= 2048;
    if (j < 2048) { p.b1[j] = p.b_ih1[j] + p.b_hh1[j]; continue; }
    j -= 2048;
    if (j < 32768) { p.h0buf[j] = p.h0_in[j]; continue; }
    j -= 32768;
    if (j < 32768) { p.h1s[j] = p.h0_in[32768 + j]; continue; }
    j -= 32768;
    if (j < 32768) { p.c0s[j] = p.c0_in[j]; continue; }
    j -= 32768;
    if (j < 32768) { p.c1s[j] = p.c0_in[32768 + j]; continue; }
    j -= 32768;
    p.feed[j] = 0.f;
    continue;
  split:
    {
      unsigned short hb = f2bf(v);
      dst[j] = hb;
      dst[N + j] = f2bf(v - bf2f(hb));
    }
  }
}

// ---------------- prep: Mw[b,s,n] = sum_k M[b,s,k] * w_in[k,n]  (f32 out) ----------------
__global__ void prep_mw(P p) {
  const int wg = blockIdx.x;             // 4096 = 128 m-blocks x 32 n-tiles
  const int bm = wg & 127, bn = wg >> 7;
  const int tid = threadIdx.x, wave = tid >> 6, lane = tid & 63;
  const int row = lane & 15, kq = (lane >> 4) * 8;
  const int m0 = bm * 64 + wave * 16;    // row into flat [B*S]
  const int n0 = bn * 16;
  const float* A = p.mbank + (size_t)(m0 + row) * HH;
  const unsigned short* Bp = p.WinT + (size_t)(n0 + row) * HH + kq;
  f32x4 acc = zero4();
  for (int kk = 0; kk < HH; kk += 32) {
    bf16x8 ah, al;
    splitA(A + kk + kq, ah, al);
    acc = mfma3(ah, al, ldb(Bp + kk), ldb(Bp + NWI + kk), acc);
  }
  const int r0 = m0 + (lane >> 4) * 4;
  const int col = n0 + row;
#pragma unroll
  for (int r = 0; r < 4; ++r)
    p.Mw[(size_t)(r0 + r) * HH + col] = acc[r];
}

// ---------------- persistent decoder ----------------
__global__ void __launch_bounds__(256) decoder_main(P p) {
  cg::grid_group grid = cg::this_grid();
  const int wg = blockIdx.x;            // 0..63
  const int tid = threadIdx.x;
  const int wave = tid >> 6, lane = tid & 63;
  const int row = lane & 15, kq = (lane >> 4) * 8;

  __shared__ float sc_lds[SS];
  __shared__ float p_lds[SS];

  for (int t = 0; t < TT; ++t) {
    const float* h0c = p.h0buf + (t & 1) * (BB * HH);
    float* h0n = p.h0buf + ((t + 1) & 1) * (BB * HH);

    // ---- P1: layer0 gates+cell (wg<32) || h1_prev @ w_hh1^T + b1 (wg>=32) ----
    if (wg < 32) {
      const int cg0 = wg * 16;
      const int m0 = wave * 16;
      const int mrow = m0 + row;
      const int tk = p.tok[t * BB + mrow];
      const float* pe = p.emb + (size_t)tk * EE;
      const float* pf = p.feed + mrow * HH;
      const float* ph = h0c + mrow * HH;
      const unsigned short* bp[4];
#pragma unroll
      for (int g = 0; g < 4; ++g)
        bp[g] = p.W0 + (size_t)(g * 512 + cg0 + row) * 1536 + kq;
      f32x4 acc[4] = {zero4(), zero4(), zero4(), zero4()};
      for (int kk = 0; kk < 1536; kk += 32) {
        const float* src; int off;
        if (kk < 512)       { src = pe; off = kk; }
        else if (kk < 1024) { src = pf; off = kk - 512; }
        else                { src = ph; off = kk - 1024; }
        bf16x8 ah, al;
        splitA(src + off + kq, ah, al);
#pragma unroll
        for (int g = 0; g < 4; ++g)
          acc[g] = mfma3(ah, al, ldb(bp[g] + kk), ldb(bp[g] + NW0 + kk), acc[g]);
      }
      const int colj = cg0 + row;
      const float bi = p.b0[colj], bff = p.b0[512 + colj];
      const float bg = p.b0[1024 + colj], bo = p.b0[1536 + colj];
#pragma unroll
      for (int r = 0; r < 4; ++r) {
        const int b = m0 + (lane >> 4) * 4 + r;
        const int idx = b * HH + colj;
        float iv = sigm(acc[0][r] + bi);
        float fv = sigm(acc[1][r] + bff);
        float gv = tanhf(acc[2][r] + bg);
        float ov = sigm(acc[3][r] + bo);
        float cn = fv * p.c0s[idx] + iv * gv;
        p.c0s[idx] = cn;
        h0n[idx] = ov * tanhf(cn);
      }
    } else {
      const int cg0 = (wg - 32) * 16;
      const int m0 = wave * 16;
      const int mrow = m0 + row;
      const float* ph1 = p.h1s + mrow * HH;
      const unsigned short* bp[4];
#pragma unroll
      for (int g = 0; g < 4; ++g)
        bp[g] = p.Whh1 + (size_t)(g * 512 + cg0 + row) * 512 + kq;
      f32x4 acc[4] = {zero4(), zero4(), zero4(), zero4()};
      for (int kk = 0; kk < 512; kk += 32) {
        bf16x8 ah, al;
        splitA(ph1 + kk + kq, ah, al);
#pragma unroll
        for (int g = 0; g < 4; ++g)
          acc[g] = mfma3(ah, al, ldb(bp[g] + kk), ldb(bp[g] + NW1 + kk), acc[g]);
      }
      const int colj = cg0 + row;
#pragma unroll
      for (int r = 0; r < 4; ++r) {
        const int b = m0 + (lane >> 4) * 4 + r;
#pragma unroll
        for (int g = 0; g < 4; ++g)
          p.part1[b * GG + g * 512 + colj] = acc[g][r] + p.b1[g * 512 + colj];
      }
    }
    grid.sync();

    // ---- P2: layer1 gates (h0n part) + cell ----
    if (wg < 32) {
      const int cg0 = wg * 16;
      const int m0 = wave * 16;
      const int mrow = m0 + row;
      const float* ph0 = h0n + mrow * HH;
      const unsigned short* bp[4];
#pragma unroll
      for (int g = 0; g < 4; ++g)
        bp[g] = p.Wih1 + (size_t)(g * 512 + cg0 + row) * 512 + kq;
      f32x4 acc[4] = {zero4(), zero4(), zero4(), zero4()};
      for (int kk = 0; kk < 512; kk += 32) {
        bf16x8 ah, al;
        splitA(ph0 + kk + kq, ah, al);
#pragma unroll
        for (int g = 0; g < 4; ++g)
          acc[g] = mfma3(ah, al, ldb(bp[g] + kk), ldb(bp[g] + NW1 + kk), acc[g]);
      }
      const int colj = cg0 + row;
#pragma unroll
      for (int r = 0; r < 4; ++r) {
        const int b = m0 + (lane >> 4) * 4 + r;
        const int idx = b * HH + colj;
        float iv = sigm(acc[0][r] + p.part1[b * GG + colj]);
        float fv = sigm(acc[1][r] + p.part1[b * GG + 512 + colj]);
        float gv = tanhf(acc[2][r] + p.part1[b * GG + 1024 + colj]);
        float ov = sigm(acc[3][r] + p.part1[b * GG + 1536 + colj]);
        float cn = fv * p.c1s[idx] + iv * gv;
        p.c1s[idx] = cn;
        p.h1s[idx] = ov * tanhf(cn);
      }
    }
    grid.sync();

    // ---- P3: attention, wg == batch index (all f32) ----
    {
      const int b = wg;
      const int lenb = p.len[b];
      float hr[8];
      {
        float4 ha = *(const float4*)(p.h1s + b * HH + lane * 8);
        float4 hb = *(const float4*)(p.h1s + b * HH + lane * 8 + 4);
        hr[0] = ha.x; hr[1] = ha.y; hr[2] = ha.z; hr[3] = ha.w;
        hr[4] = hb.x; hr[5] = hb.y; hr[6] = hb.z; hr[7] = hb.w;
      }
      const float* MwB = p.Mw + (size_t)b * SS * HH;
      for (int i = 0; i < 32; ++i) {
        const int s = wave * 32 + i;
        float4 m0v = *(const float4*)(MwB + (size_t)s * HH + lane * 8);
        float4 m1v = *(const float4*)(MwB + (size_t)s * HH + lane * 8 + 4);
        float d = hr[0] * m0v.x + hr[1] * m0v.y + hr[2] * m0v.z + hr[3] * m0v.w
                + hr[4] * m1v.x + hr[5] * m1v.y + hr[6] * m1v.z + hr[7] * m1v.w;
#pragma unroll
        for (int o = 32; o; o >>= 1) d += __shfl_xor(d, o);
        if (lane == 0) sc_lds[s] = (s < lenb) ? d : -__builtin_inff();
      }
      __syncthreads();
      if (wave == 0) {
        float s0 = sc_lds[lane], s1 = sc_lds[lane + 64];
        float mx = fmaxf(s0, s1);
#pragma unroll
        for (int o = 32; o; o >>= 1) mx = fmaxf(mx, __shfl_xor(mx, o));
        float e0 = (lane < lenb) ? __expf(s0 - mx) : 0.f;
        float e1 = (lane + 64 < lenb) ? __expf(s1 - mx) : 0.f;
        float sm = e0 + e1;
#pragma unroll
        for (int o = 32; o; o >>= 1) sm += __shfl_xor(sm, o);
        float inv = 1.f / sm;
        float p0 = e0 * inv, p1 = e1 * inv;
        p_lds[lane] = p0; p_lds[lane + 64] = p1;
        float* ao = p.out_attn + ((size_t)t * BB + b) * SS;
        ao[lane] = p0; ao[lane + 64] = p1;
      }
      __syncthreads();
      const float* MbB = p.mbank + (size_t)b * SS * HH;
      const int h2 = tid * 2;
      float ca = 0.f, cb = 0.f;
#pragma unroll 4
      for (int s = 0; s < SS; ++s) {
        float ps = p_lds[s];
        float2 v = *(const float2*)(MbB + (size_t)s * HH + h2);
        ca += ps * v.x;
        cb += ps * v.y;
      }
      p.ctx[b * HH + h2] = ca;
      p.ctx[b * HH + h2 + 1] = cb;
    }
    grid.sync();

    // ---- P4: attn_h = tanh([ctx | h1n] @ w_out^T) -> dec_out, feed ----
    if (wg < 32) {
      const int n0 = wg * 16;
      const int m0 = wave * 16;
      const int mrow = m0 + row;
      const float* pc = p.ctx + mrow * HH;
      const float* ph1 = p.h1s + mrow * HH;
      const unsigned short* bp = p.Wout + (size_t)(n0 + row) * 1024 + kq;
      f32x4 acc = zero4();
      for (int kk = 0; kk < 1024; kk += 32) {
        const float* src = (kk < 512) ? pc : ph1;
        const int off = (kk < 512) ? kk : kk - 512;
        bf16x8 ah, al;
        splitA(src + off + kq, ah, al);
        acc = mfma3(ah, al, ldb(bp + kk), ldb(bp + NWO + kk), acc);
      }
      float* dec = p.out_dec + (size_t)t * BB * HH;
      const int j = n0 + row;
#pragma unroll
      for (int r = 0; r < 4; ++r) {
        const int b = m0 + (lane >> 4) * 4 + r;
        float v = tanhf(acc[r]);
        dec[b * HH + j] = v;
        p.feed[b * HH + j] = v;
      }
    }
    grid.sync();
  }

  // ---- final states ----
  {
    const int gt = wg * 256 + tid;
    const float* hf0 = p.h0buf + (TT & 1) * (BB * HH);  // TT even -> buf 0
    for (int i = gt; i < BB * HH; i += 64 * 256) {
      p.out_hf[i] = hf0[i];
      p.out_hf[BB * HH + i] = p.h1s[i];
      p.out_cf[i] = p.c0s[i];
      p.out_cf[BB * HH + i] = p.c1s[i];
    }
  }
}

extern "C" void kernel_launch(void* const* d_in, const int* in_sizes, int n_in,
                              void* d_out, int out_size, void* d_ws, size_t ws_size,
                              hipStream_t stream) {
  P p;
  p.tok   = (const int*)d_in[0];
  p.mbank = (const float*)d_in[1];
  p.len   = (const int*)d_in[2];
  p.h0_in = (const float*)d_in[3];
  p.c0_in = (const float*)d_in[4];
  p.emb   = (const float*)d_in[5];
  p.w_ih0 = (const float*)d_in[6];
  p.w_hh0 = (const float*)d_in[7];
  p.b_ih0 = (const float*)d_in[8];
  p.b_hh0 = (const float*)d_in[9];
  p.w_ih1 = (const float*)d_in[10];
  p.w_hh1 = (const float*)d_in[11];
  p.b_ih1 = (const float*)d_in[12];
  p.b_hh1 = (const float*)d_in[13];
  p.w_in  = (const float*)d_in[14];
  p.w_out = (const float*)d_in[15];

  float* out = (float*)d_out;
  p.out_dec  = out;
  p.out_attn = out + (size_t)TT * BB * HH;
  p.out_hf   = out + (size_t)TT * BB * HH + (size_t)TT * BB * SS;
  p.out_cf   = p.out_hf + 2 * BB * HH;

  char* w = (char*)d_ws;
  auto alloc = [&](size_t n) { char* r = w; w += (n + 255) & ~(size_t)255; return r; };
  p.W0    = (unsigned short*)alloc((size_t)NW0 * 2 * 2);   // hi+lo
  p.Wih1  = (unsigned short*)alloc((size_t)NW1 * 2 * 2);
  p.Whh1  = (unsigned short*)alloc((size_t)NW1 * 2 * 2);
  p.Wout  = (unsigned short*)alloc((size_t)NWO * 2 * 2);
  p.WinT  = (unsigned short*)alloc((size_t)NWI * 2 * 2);
  p.Mw    = (float*)alloc((size_t)BB * SS * HH * 4);
  p.b0    = (float*)alloc(2048 * 4);
  p.b1    = (float*)alloc(2048 * 4);
  p.h0buf = (float*)alloc((size_t)2 * BB * HH * 4);
  p.h1s   = (float*)alloc((size_t)BB * HH * 4);
  p.c0s   = (float*)alloc((size_t)BB * HH * 4);
  p.c1s   = (float*)alloc((size_t)BB * HH * 4);
  p.feed  = (float*)alloc((size_t)BB * HH * 4);
  p.part1 = (float*)alloc((size_t)BB * GG * 4);
  p.ctx   = (float*)alloc((size_t)BB * HH * 4);

  hipLaunchKernelGGL(prep_weights, dim3(4096), dim3(256), 0, stream, p);
  hipLaunchKernelGGL(prep_mw, dim3(4096), dim3(256), 0, stream, p);
  void* args[] = {(void*)&p};
  hipLaunchCooperativeKernel((void*)decoder_main, dim3(64), dim3(256), args, 0, stream);
}

// Round 5
// 12579.424 us; speedup vs baseline: 1.0392x; 1.0392x over previous
//
#include <hip/hip_runtime.h>
#include <hip/hip_bf16.h>
#include <hip/hip_cooperative_groups.h>

namespace cg = cooperative_groups;

typedef __bf16 bf16x8 __attribute__((ext_vector_type(8)));
typedef unsigned short u16x8 __attribute__((ext_vector_type(8)));
typedef float f32x4 __attribute__((ext_vector_type(4)));

constexpr int TT = 64;   // timesteps
constexpr int BB = 64;   // batch
constexpr int SS = 128;  // memory length
constexpr int HH = 512;  // hidden
constexpr int GG = 2048; // 4*H

// weight sizes (elements); hi at [0], lo at [N]
constexpr int NW0E = 2048 * 512;
constexpr int NW0R = 2048 * 1024;
constexpr int NW1  = 2048 * 512;
constexpr int NWO  = 512 * 1024;
constexpr int NWI  = 512 * 512;

struct P {
  const int* tok; const float* mbank; const int* len;
  const float* h0_in; const float* c0_in; const float* emb;
  const float* w_ih0; const float* w_hh0; const float* b_ih0; const float* b_hh0;
  const float* w_ih1; const float* w_hh1; const float* b_ih1; const float* b_hh1;
  const float* w_in; const float* w_out;
  float* out_dec; float* out_attn; float* out_hf; float* out_cf;
  unsigned short *W0E, *W0R, *Wih1, *Whh1, *Wout, *WinT;
  float *EGb;                             // f32: score-path precision
  float *Mw;
  float *b0, *b1, *h0buf, *h1s, *c0s, *c1s, *feed, *part1, *ctx, *scg;
  unsigned int* flag;
};

__device__ __forceinline__ unsigned short f2bf(float f) {
  unsigned int u = __builtin_bit_cast(unsigned int, f);
  return (unsigned short)((u + 0x7fffu + ((u >> 16) & 1u)) >> 16);
}
__device__ __forceinline__ float bf2f(unsigned short h) {
  return __builtin_bit_cast(float, ((unsigned int)h) << 16);
}
__device__ __forceinline__ bf16x8 ldb(const unsigned short* p) {
  return __builtin_bit_cast(bf16x8, *(const u16x8*)p);
}
__device__ __forceinline__ f32x4 mfma_(bf16x8 a, bf16x8 b, f32x4 c) {
  return __builtin_amdgcn_mfma_f32_16x16x32_bf16(a, b, c, 0, 0, 0);
}
__device__ __forceinline__ float sigm(float x) { return 1.f / (1.f + __expf(-x)); }
__device__ __forceinline__ f32x4 zero4() { f32x4 z = {0.f, 0.f, 0.f, 0.f}; return z; }

__device__ __forceinline__ void splitA(const float* s, bf16x8& hi, bf16x8& lo) {
  float4 a0 = *(const float4*)s;
  float4 a1 = *(const float4*)(s + 4);
  float v[8] = {a0.x, a0.y, a0.z, a0.w, a1.x, a1.y, a1.z, a1.w};
  u16x8 h, l;
#pragma unroll
  for (int j = 0; j < 8; ++j) {
    unsigned short hb = f2bf(v[j]);
    h[j] = hb;
    l[j] = f2bf(v[j] - bf2f(hb));
  }
  hi = __builtin_bit_cast(bf16x8, h);
  lo = __builtin_bit_cast(bf16x8, l);
}
__device__ __forceinline__ f32x4 mfma3(bf16x8 ah, bf16x8 al, bf16x8 bh, bf16x8 bl, f32x4 c) {
  c = mfma_(al, bh, c);
  c = mfma_(ah, bl, c);
  c = mfma_(ah, bh, c);
  return c;
}

// ---------------- prep: weight split / transpose / state init ----------------
__global__ void prep_weights(P p) {
  constexpr int TOT = NW0E + NW0R + NW1 + NW1 + NWO + NWI + 2048 + 2048 +
                      32768 * 5 + 8192 + 64;
  for (int i = blockIdx.x * blockDim.x + threadIdx.x; i < TOT;
       i += gridDim.x * blockDim.x) {
    int j = i;
    float v; unsigned short* dst; int N;
    if (j < NW0E) {              // emb part of w_ih0: [2048][512]
      int n = j >> 9, k = j & 511;
      v = p.w_ih0[n * 1024 + k];
      dst = p.W0E; N = NW0E; goto split;
    }
    j -= NW0E;
    if (j < NW0R) {              // [feed | h] : [2048][1024]
      int n = j >> 10, k = j & 1023;
      v = (k < 512) ? p.w_ih0[n * 1024 + 512 + k] : p.w_hh0[n * 512 + (k - 512)];
      dst = p.W0R; N = NW0R; goto split;
    }
    j -= NW0R;
    if (j < NW1) { v = p.w_ih1[j]; dst = p.Wih1; N = NW1; goto split; }
    j -= NW1;
    if (j < NW1) { v = p.w_hh1[j]; dst = p.Whh1; N = NW1; goto split; }
    j -= NW1;
    if (j < NWO) { v = p.w_out[j]; dst = p.Wout; N = NWO; goto split; }
    j -= NWO;
    if (j < NWI) {               // WinT[n][k] = w_in[k][n]
      int n = j >> 9, q = j & 511;
      v = p.w_in[q * 512 + n];
      dst = p.WinT; N = NWI; goto split;
    }
    j -= NWI;
    if (j < 2048) { p.b0[j] = p.b_ih0[j] + p.b_hh0[j]; continue; }
    j -= 2048;
    if (j < 2048) { p.b1[j] = p.b_ih1[j] + p.b_hh1[j]; continue; }
    j -= 2048;
    if (j < 32768) { p.h0buf[j] = p.h0_in[j]; continue; }
    j -= 32768;
    if (j < 32768) { p.h1s[j] = p.h0_in[32768 + j]; continue; }
    j -= 32768;
    if (j < 32768) { p.c0s[j] = p.c0_in[j]; continue; }
    j -= 32768;
    if (j < 32768) { p.c1s[j] = p.c0_in[32768 + j]; continue; }
    j -= 32768;
    if (j < 32768) { p.feed[j] = 0.f; continue; }
    j -= 32768;
    if (j < 8192) { p.scg[j] = 0.f; continue; }
    j -= 8192;
    p.flag[j] = 0u;
    continue;
  split:
    {
      unsigned short hb = f2bf(v);
      dst[j] = hb;
      dst[N + j] = f2bf(v - bf2f(hb));
    }
  }
}

// ---------------- prep: Mw[b,s,n] = sum_k M[b,s,k] * w_in[k,n]  (f32) ----------------
__global__ void prep_mw(P p) {
  const int wg = blockIdx.x;             // 4096 = 128 m-blocks x 32 n-tiles
  const int bm = wg & 127, bn = wg >> 7;
  const int tid = threadIdx.x, wave = tid >> 6, lane = tid & 63;
  const int arow = lane & 15, kq = (lane >> 4) * 8;
  const int m0 = bm * 64 + wave * 16;
  const int n0 = bn * 16;
  const float* A = p.mbank + (size_t)(m0 + arow) * HH;
  const unsigned short* Bp = p.WinT + (size_t)(n0 + arow) * HH + kq;
  f32x4 acc = zero4();
  for (int kk = 0; kk < HH; kk += 32) {
    bf16x8 ah, al;
    splitA(A + kk + kq, ah, al);
    acc = mfma3(ah, al, ldb(Bp + kk), ldb(Bp + NWI + kk), acc);
  }
  const int r0 = m0 + (lane >> 4) * 4;
#pragma unroll
  for (int r = 0; r < 4; ++r)
    p.Mw[(size_t)(r0 + r) * HH + n0 + arow] = acc[r];
}

// ---------------- prep: EGb[t*64+b, n] = emb[tok] @ W0E^T + b0  (f32) ----------------
__global__ void prep_eg(P p) {
  const int wg = blockIdx.x;             // 8192 = 64 m-blocks x 128 n-tiles
  const int bn = wg & 127, bm = wg >> 7;
  const int tid = threadIdx.x, wave = tid >> 6, lane = tid & 63;
  const int arow = lane & 15, kq = (lane >> 4) * 8;
  const int m0 = bm * 64 + wave * 16;    // flat row in [0,4096)
  const int n0 = bn * 16;
  const int token = p.tok[m0 + arow];
  const float* A = p.emb + (size_t)token * 512;
  const unsigned short* Bp = p.W0E + (size_t)(n0 + arow) * 512 + kq;
  f32x4 acc = zero4();
  for (int kk = 0; kk < 512; kk += 32) {
    bf16x8 ah, al;
    splitA(A + kk + kq, ah, al);
    acc = mfma3(ah, al, ldb(Bp + kk), ldb(Bp + NW0E + kk), acc);
  }
  const int r0 = m0 + (lane >> 4) * 4;
  const float bb = p.b0[n0 + arow];
#pragma unroll
  for (int r = 0; r < 4; ++r)
    p.EGb[(size_t)(r0 + r) * 2048 + n0 + arow] = acc[r] + bb;
}

// ---------------- persistent decoder: 256 WGs x 256 threads ----------------
__global__ void __launch_bounds__(256) decoder_main(P p) {
  cg::grid_group grid = cg::this_grid();
  const int wg = blockIdx.x, tid = threadIdx.x;
  const int wave = tid >> 6, lane = tid & 63;
  const int arow = lane & 15;            // fragment row (A: m, B: n)
  const int kq = (lane >> 4) * 8;

  __shared__ float MwL[32][512];          // 64 KB, pinned: Mw quarter (f32)
  __shared__ float Aslab[16][516];        // 33 KB, staged GEMM A operand
  __shared__ float exch[4][16][16];       // gate exchange
  __shared__ float scl[128];
  __shared__ float pl[128];

  const int attb = wg >> 2, attq = wg & 3;
  // pin score-matrix LDS (prep output; coherent at kernel launch)
  for (int idx = tid; idx < 32 * 512; idx += 256) {
    int r = idx >> 9, c = idx & 511;
    MwL[r][c] = p.Mw[(size_t)(attb * 128 + attq * 32 + r) * 512 + c];
  }

  const int w2 = (wg < 128) ? wg : wg - 128;
  const int strip = w2 & 31;             // 16-col strip within a gate (512/16)
  const int mblk = w2 >> 5;              // 16-row batch block (64/16)
  const int gate = wave;                 // wave-per-gate
  const int colj = strip * 16 + arow;

  auto stage = [&](const float* base) {  // [16][512] row-major -> Aslab
    __syncthreads();
    for (int idx = tid * 4; idx < 16 * 512; idx += 1024) {
      int r = idx >> 9, c = idx & 511;
      float4 v = *(const float4*)(base + r * 512 + c);
      *(float4*)&Aslab[r][c] = v;
    }
    __syncthreads();
  };
  auto gemm_half = [&](const unsigned short* whi, const unsigned short* wlo,
                       f32x4 acc) {
#pragma unroll 4
    for (int kk = 0; kk < 512; kk += 32) {
      bf16x8 ah, al;
      splitA(&Aslab[arow][kk + kq], ah, al);
      acc = mfma3(ah, al, ldb(whi + kk), ldb(wlo + kk), acc);
    }
    return acc;
  };

  for (int t = 0; t < TT; ++t) {
    const float* h0c = p.h0buf + (t & 1) * (BB * HH);
    float* h0n = p.h0buf + ((t + 1) & 1) * (BB * HH);

    // ---- P1: gates0+cell0 (wg<128) || h1_prev @ Whh1 + b1 (wg>=128) ----
    if (wg < 128) {
      const size_t wr = (size_t)(gate * 512 + colj) * 1024;
      f32x4 acc = zero4();
      stage(p.feed + mblk * 16 * 512);
      acc = gemm_half(p.W0R + wr + kq, p.W0R + NW0R + wr + kq, acc);
      stage(h0c + mblk * 16 * 512);
      acc = gemm_half(p.W0R + wr + 512 + kq, p.W0R + NW0R + wr + 512 + kq, acc);
      const float* eg =
          p.EGb + ((size_t)(t * 64 + mblk * 16)) * 2048 + gate * 512 + colj;
#pragma unroll
      for (int r = 0; r < 4; ++r) {
        acc[r] += eg[((lane >> 4) * 4 + r) * 2048];
        exch[gate][(lane >> 4) * 4 + r][arow] = acc[r];
      }
      __syncthreads();
      {
        int br = tid >> 4, nc = tid & 15;
        int idx = (mblk * 16 + br) * 512 + strip * 16 + nc;
        float iv = sigm(exch[0][br][nc]);
        float fv = sigm(exch[1][br][nc]);
        float gv = tanhf(exch[2][br][nc]);
        float ov = sigm(exch[3][br][nc]);
        float cn = fv * p.c0s[idx] + iv * gv;
        p.c0s[idx] = cn;
        h0n[idx] = ov * tanhf(cn);
      }
    } else {
      const size_t wr = (size_t)(gate * 512 + colj) * 512;
      stage(p.h1s + mblk * 16 * 512);
      f32x4 acc = gemm_half(p.Whh1 + wr + kq, p.Whh1 + NW1 + wr + kq, zero4());
      const float bb = p.b1[gate * 512 + colj];
#pragma unroll
      for (int r = 0; r < 4; ++r)
        p.part1[(mblk * 16 + (lane >> 4) * 4 + r) * 2048 + gate * 512 + colj] =
            acc[r] + bb;
    }
    grid.sync();

    // ---- P2: gates1(ih part) + part1 + cell1 (wg<128); ctx zero (128..159) ----
    if (wg < 128) {
      const size_t wr = (size_t)(gate * 512 + colj) * 512;
      stage(h0n + mblk * 16 * 512);
      f32x4 acc = gemm_half(p.Wih1 + wr + kq, p.Wih1 + NW1 + wr + kq, zero4());
#pragma unroll
      for (int r = 0; r < 4; ++r) {
        acc[r] += p.part1[(mblk * 16 + (lane >> 4) * 4 + r) * 2048 +
                          gate * 512 + colj];
        exch[gate][(lane >> 4) * 4 + r][arow] = acc[r];
      }
      __syncthreads();
      {
        int br = tid >> 4, nc = tid & 15;
        int idx = (mblk * 16 + br) * 512 + strip * 16 + nc;
        float iv = sigm(exch[0][br][nc]);
        float fv = sigm(exch[1][br][nc]);
        float gv = tanhf(exch[2][br][nc]);
        float ov = sigm(exch[3][br][nc]);
        float cn = fv * p.c1s[idx] + iv * gv;
        p.c1s[idx] = cn;
        p.h1s[idx] = ov * tanhf(cn);
      }
    } else if (wg < 160) {
      int base = (wg - 128) * 1024 + tid * 4;
#pragma unroll
      for (int i = 0; i < 4; ++i) atomicExch(&p.ctx[base + i], 0.f);
    }
    grid.sync();

    // ---- P3: attention (4 WGs per batch; scores from LDS Mw, ctx from f32 mbank) ----
    {
      float h8[8];
      {
        float4 a = *(const float4*)(p.h1s + attb * 512 + lane * 8);
        float4 c = *(const float4*)(p.h1s + attb * 512 + lane * 8 + 4);
        h8[0] = a.x; h8[1] = a.y; h8[2] = a.z; h8[3] = a.w;
        h8[4] = c.x; h8[5] = c.y; h8[6] = c.z; h8[7] = c.w;
      }
#pragma unroll
      for (int i = 0; i < 8; ++i) {
        const int sl = wave * 8 + i;
        const float* mw = &MwL[sl][lane * 8];
        float d = h8[0] * mw[0] + h8[1] * mw[1] + h8[2] * mw[2] + h8[3] * mw[3] +
                  h8[4] * mw[4] + h8[5] * mw[5] + h8[6] * mw[6] + h8[7] * mw[7];
#pragma unroll
        for (int o = 32; o; o >>= 1) d += __shfl_xor(d, o);
        if (lane == 0) atomicExch(&p.scg[attb * 128 + attq * 32 + sl], d);
      }
      __syncthreads();
      __threadfence();
      if (tid == 0) {
        atomicAdd(&p.flag[attb], 1u);
        const unsigned tgt = 4u * (unsigned)(t + 1);
        while (atomicAdd(&p.flag[attb], 0u) < tgt) __builtin_amdgcn_s_sleep(2);
      }
      __syncthreads();
      __threadfence();
      if (tid < 128) scl[tid] = atomicAdd(&p.scg[attb * 128 + tid], 0.f);
      __syncthreads();
      if (wave == 0) {
        const int lenb = p.len[attb];
        float s0 = (lane < lenb) ? scl[lane] : -__builtin_inff();
        float s1 = (lane + 64 < lenb) ? scl[lane + 64] : -__builtin_inff();
        float mx = fmaxf(s0, s1);
#pragma unroll
        for (int o = 32; o; o >>= 1) mx = fmaxf(mx, __shfl_xor(mx, o));
        float e0 = (lane < lenb) ? __expf(s0 - mx) : 0.f;
        float e1 = (lane + 64 < lenb) ? __expf(s1 - mx) : 0.f;
        float sm = e0 + e1;
#pragma unroll
        for (int o = 32; o; o >>= 1) sm += __shfl_xor(sm, o);
        float inv = 1.f / sm;
        pl[lane] = e0 * inv; pl[lane + 64] = e1 * inv;
        if (attq == 0) {
          float* ao = p.out_attn + ((size_t)t * BB + attb) * SS;
          ao[lane] = e0 * inv; ao[lane + 64] = e1 * inv;
        }
      }
      __syncthreads();
      {
        const float* MbB = p.mbank + (size_t)(attb * 128 + attq * 32) * 512;
        const int h2 = tid * 2;
        float ca = 0.f, cb = 0.f;
#pragma unroll 4
        for (int s = 0; s < 32; ++s) {
          float ps = pl[attq * 32 + s];
          float2 v = *(const float2*)(MbB + (size_t)s * 512 + h2);
          ca += ps * v.x;
          cb += ps * v.y;
        }
        atomicAdd(&p.ctx[attb * 512 + h2], ca);
        atomicAdd(&p.ctx[attb * 512 + h2 + 1], cb);
      }
    }
    grid.sync();

    // ---- P4: attn_h = tanh([ctx | h1] @ Wout^T) -> out_dec, feed ----
    if (wg < 32) {
      const int m4 = wg >> 3, ngrp = wg & 7;
      const int nstrip = ngrp * 4 + wave;
      const int cj = nstrip * 16 + arow;
      const size_t wr = (size_t)cj * 1024;
      f32x4 acc = zero4();
      stage(p.ctx + m4 * 16 * 512);
      acc = gemm_half(p.Wout + wr + kq, p.Wout + NWO + wr + kq, acc);
      stage(p.h1s + m4 * 16 * 512);
      acc = gemm_half(p.Wout + wr + 512 + kq, p.Wout + NWO + wr + 512 + kq, acc);
      float* dec = p.out_dec + (size_t)t * BB * HH;
#pragma unroll
      for (int r = 0; r < 4; ++r) {
        int b = m4 * 16 + (lane >> 4) * 4 + r;
        float v = tanhf(acc[r]);
        dec[b * 512 + cj] = v;
        p.feed[b * 512 + cj] = v;
      }
    }
    grid.sync();
  }

  // ---- final states ----
  for (int i = wg * 256 + tid; i < BB * HH; i += 256 * 256) {
    p.out_hf[i] = p.h0buf[i];            // TT even -> buffer 0
    p.out_hf[BB * HH + i] = p.h1s[i];
    p.out_cf[i] = p.c0s[i];
    p.out_cf[BB * HH + i] = p.c1s[i];
  }
}

extern "C" void kernel_launch(void* const* d_in, const int* in_sizes, int n_in,
                              void* d_out, int out_size, void* d_ws, size_t ws_size,
                              hipStream_t stream) {
  P p;
  p.tok   = (const int*)d_in[0];
  p.mbank = (const float*)d_in[1];
  p.len   = (const int*)d_in[2];
  p.h0_in = (const float*)d_in[3];
  p.c0_in = (const float*)d_in[4];
  p.emb   = (const float*)d_in[5];
  p.w_ih0 = (const float*)d_in[6];
  p.w_hh0 = (const float*)d_in[7];
  p.b_ih0 = (const float*)d_in[8];
  p.b_hh0 = (const float*)d_in[9];
  p.w_ih1 = (const float*)d_in[10];
  p.w_hh1 = (const float*)d_in[11];
  p.b_ih1 = (const float*)d_in[12];
  p.b_hh1 = (const float*)d_in[13];
  p.w_in  = (const float*)d_in[14];
  p.w_out = (const float*)d_in[15];

  float* out = (float*)d_out;
  p.out_dec  = out;
  p.out_attn = out + (size_t)TT * BB * HH;
  p.out_hf   = out + (size_t)TT * BB * HH + (size_t)TT * BB * SS;
  p.out_cf   = p.out_hf + 2 * BB * HH;

  char* w = (char*)d_ws;
  auto alloc = [&](size_t n) { char* r = w; w += (n + 255) & ~(size_t)255; return r; };
  p.W0E   = (unsigned short*)alloc((size_t)NW0E * 2 * 2);
  p.W0R   = (unsigned short*)alloc((size_t)NW0R * 2 * 2);
  p.Wih1  = (unsigned short*)alloc((size_t)NW1 * 2 * 2);
  p.Whh1  = (unsigned short*)alloc((size_t)NW1 * 2 * 2);
  p.Wout  = (unsigned short*)alloc((size_t)NWO * 2 * 2);
  p.WinT  = (unsigned short*)alloc((size_t)NWI * 2 * 2);
  p.EGb   = (float*)alloc((size_t)4096 * 2048 * 4);
  p.Mw    = (float*)alloc((size_t)BB * SS * HH * 4);
  p.b0    = (float*)alloc(2048 * 4);
  p.b1    = (float*)alloc(2048 * 4);
  p.h0buf = (float*)alloc((size_t)2 * BB * HH * 4);
  p.h1s   = (float*)alloc((size_t)BB * HH * 4);
  p.c0s   = (float*)alloc((size_t)BB * HH * 4);
  p.c1s   = (float*)alloc((size_t)BB * HH * 4);
  p.feed  = (float*)alloc((size_t)BB * HH * 4);
  p.part1 = (float*)alloc((size_t)BB * GG * 4);
  p.ctx   = (float*)alloc((size_t)BB * HH * 4);
  p.scg   = (float*)alloc((size_t)BB * SS * 4);
  p.flag  = (unsigned int*)alloc(64 * 4);

  hipLaunchKernelGGL(prep_weights, dim3(4096), dim3(256), 0, stream, p);
  hipLaunchKernelGGL(prep_mw, dim3(4096), dim3(256), 0, stream, p);
  hipLaunchKernelGGL(prep_eg, dim3(8192), dim3(256), 0, stream, p);
  void* args[] = {(void*)&p};
  hipLaunchCooperativeKernel((void*)decoder_main, dim3(256), dim3(256), args, 0, stream);
}

// Round 6
// 8807.198 us; speedup vs baseline: 1.4844x; 1.4283x over previous
//
#include <hip/hip_runtime.h>
#include <hip/hip_bf16.h>

typedef __bf16 bf16x8 __attribute__((ext_vector_type(8)));
typedef unsigned short u16x8 __attribute__((ext_vector_type(8)));
typedef float f32x4 __attribute__((ext_vector_type(4)));

constexpr int TT = 64;   // timesteps
constexpr int BB = 64;   // batch
constexpr int SS = 128;  // memory length
constexpr int HH = 512;  // hidden
constexpr int GG = 2048; // 4*H

// weight sizes (elements); hi at [0], lo at [N]
constexpr int NW0E = 2048 * 512;
constexpr int NW0R = 2048 * 1024;
constexpr int NW1  = 2048 * 512;
constexpr int NWO  = 512 * 1024;
constexpr int NWI  = 512 * 512;

struct P {
  const int* tok; const float* mbank; const int* len;
  const float* h0_in; const float* c0_in; const float* emb;
  const float* w_ih0; const float* w_hh0; const float* b_ih0; const float* b_hh0;
  const float* w_ih1; const float* w_hh1; const float* b_ih1; const float* b_hh1;
  const float* w_in; const float* w_out;
  float* out_dec; float* out_attn; float* out_hf; float* out_cf;
  unsigned short *W0E, *W0R, *Wih1, *Whh1, *Wout, *WinT;
  float *EGb;                             // f32: score-path precision
  float *Mw;
  float *b0, *b1, *h0buf, *h1s, *c0s, *c1s, *feed, *part1, *ctx, *scg;
  unsigned int* flag;                     // [0..63] P3 groups, [64] grid barrier
};

__device__ __forceinline__ unsigned short f2bf(float f) {
  unsigned int u = __builtin_bit_cast(unsigned int, f);
  return (unsigned short)((u + 0x7fffu + ((u >> 16) & 1u)) >> 16);
}
__device__ __forceinline__ float bf2f(unsigned short h) {
  return __builtin_bit_cast(float, ((unsigned int)h) << 16);
}
__device__ __forceinline__ bf16x8 ldb(const unsigned short* p) {
  return __builtin_bit_cast(bf16x8, *(const u16x8*)p);
}
__device__ __forceinline__ f32x4 mfma_(bf16x8 a, bf16x8 b, f32x4 c) {
  return __builtin_amdgcn_mfma_f32_16x16x32_bf16(a, b, c, 0, 0, 0);
}
__device__ __forceinline__ float sigm(float x) { return 1.f / (1.f + __expf(-x)); }
__device__ __forceinline__ f32x4 zero4() { f32x4 z = {0.f, 0.f, 0.f, 0.f}; return z; }

// ---- fast grid barrier: monotonic LLC counter, tid0 arrive/spin, tid0 fences ----
__device__ __forceinline__ void gbar(unsigned* ctr, unsigned target) {
  __syncthreads();                       // WG stores drained (vmcnt 0 per wave)
  if (threadIdx.x == 0) {
    __threadfence();                     // release: L2 writeback (device scope)
    __hip_atomic_fetch_add(ctr, 1u, __ATOMIC_RELAXED, __HIP_MEMORY_SCOPE_AGENT);
    while (__hip_atomic_load(ctr, __ATOMIC_RELAXED, __HIP_MEMORY_SCOPE_AGENT) < target)
      __builtin_amdgcn_s_sleep(2);
    __threadfence();                     // acquire: L2/L1 invalidate
  }
  __syncthreads();
}

__device__ __forceinline__ void splitA(const float* s, bf16x8& hi, bf16x8& lo) {
  float4 a0 = *(const float4*)s;
  float4 a1 = *(const float4*)(s + 4);
  float v[8] = {a0.x, a0.y, a0.z, a0.w, a1.x, a1.y, a1.z, a1.w};
  u16x8 h, l;
#pragma unroll
  for (int j = 0; j < 8; ++j) {
    unsigned short hb = f2bf(v[j]);
    h[j] = hb;
    l[j] = f2bf(v[j] - bf2f(hb));
  }
  hi = __builtin_bit_cast(bf16x8, h);
  lo = __builtin_bit_cast(bf16x8, l);
}
__device__ __forceinline__ f32x4 mfma3(bf16x8 ah, bf16x8 al, bf16x8 bh, bf16x8 bl, f32x4 c) {
  c = mfma_(al, bh, c);
  c = mfma_(ah, bl, c);
  c = mfma_(ah, bh, c);
  return c;
}

// ---------------- prep: weight split / transpose / state init ----------------
__global__ void prep_weights(P p) {
  constexpr int TOT = NW0E + NW0R + NW1 + NW1 + NWO + NWI + 2048 + 2048 +
                      32768 * 5 + 8192 + 128;
  for (int i = blockIdx.x * blockDim.x + threadIdx.x; i < TOT;
       i += gridDim.x * blockDim.x) {
    int j = i;
    float v; unsigned short* dst; int N;
    if (j < NW0E) {              // emb part of w_ih0: [2048][512]
      int n = j >> 9, k = j & 511;
      v = p.w_ih0[n * 1024 + k];
      dst = p.W0E; N = NW0E; goto split;
    }
    j -= NW0E;
    if (j < NW0R) {              // [feed | h] : [2048][1024]
      int n = j >> 10, k = j & 1023;
      v = (k < 512) ? p.w_ih0[n * 1024 + 512 + k] : p.w_hh0[n * 512 + (k - 512)];
      dst = p.W0R; N = NW0R; goto split;
    }
    j -= NW0R;
    if (j < NW1) { v = p.w_ih1[j]; dst = p.Wih1; N = NW1; goto split; }
    j -= NW1;
    if (j < NW1) { v = p.w_hh1[j]; dst = p.Whh1; N = NW1; goto split; }
    j -= NW1;
    if (j < NWO) { v = p.w_out[j]; dst = p.Wout; N = NWO; goto split; }
    j -= NWO;
    if (j < NWI) {               // WinT[n][k] = w_in[k][n]
      int n = j >> 9, q = j & 511;
      v = p.w_in[q * 512 + n];
      dst = p.WinT; N = NWI; goto split;
    }
    j -= NWI;
    if (j < 2048) { p.b0[j] = p.b_ih0[j] + p.b_hh0[j]; continue; }
    j -= 2048;
    if (j < 2048) { p.b1[j] = p.b_ih1[j] + p.b_hh1[j]; continue; }
    j -= 2048;
    if (j < 32768) { p.h0buf[j] = p.h0_in[j]; continue; }
    j -= 32768;
    if (j < 32768) { p.h1s[j] = p.h0_in[32768 + j]; continue; }
    j -= 32768;
    if (j < 32768) { p.c0s[j] = p.c0_in[j]; continue; }
    j -= 32768;
    if (j < 32768) { p.c1s[j] = p.c0_in[32768 + j]; continue; }
    j -= 32768;
    if (j < 32768) { p.feed[j] = 0.f; continue; }
    j -= 32768;
    if (j < 8192) { p.scg[j] = 0.f; continue; }
    j -= 8192;
    p.flag[j] = 0u;
    continue;
  split:
    {
      unsigned short hb = f2bf(v);
      dst[j] = hb;
      dst[N + j] = f2bf(v - bf2f(hb));
    }
  }
}

// ---------------- prep: Mw[b,s,n] = sum_k M[b,s,k] * w_in[k,n]  (f32) ----------------
__global__ void prep_mw(P p) {
  const int wg = blockIdx.x;             // 4096 = 128 m-blocks x 32 n-tiles
  const int bm = wg & 127, bn = wg >> 7;
  const int tid = threadIdx.x, wave = tid >> 6, lane = tid & 63;
  const int arow = lane & 15, kq = (lane >> 4) * 8;
  const int m0 = bm * 64 + wave * 16;
  const int n0 = bn * 16;
  const float* A = p.mbank + (size_t)(m0 + arow) * HH;
  const unsigned short* Bp = p.WinT + (size_t)(n0 + arow) * HH + kq;
  f32x4 acc = zero4();
  for (int kk = 0; kk < HH; kk += 32) {
    bf16x8 ah, al;
    splitA(A + kk + kq, ah, al);
    acc = mfma3(ah, al, ldb(Bp + kk), ldb(Bp + NWI + kk), acc);
  }
  const int r0 = m0 + (lane >> 4) * 4;
#pragma unroll
  for (int r = 0; r < 4; ++r)
    p.Mw[(size_t)(r0 + r) * HH + n0 + arow] = acc[r];
}

// ---------------- prep: EGb[t*64+b, n] = emb[tok] @ W0E^T + b0  (f32) ----------------
__global__ void prep_eg(P p) {
  const int wg = blockIdx.x;             // 8192 = 64 m-blocks x 128 n-tiles
  const int bn = wg & 127, bm = wg >> 7;
  const int tid = threadIdx.x, wave = tid >> 6, lane = tid & 63;
  const int arow = lane & 15, kq = (lane >> 4) * 8;
  const int m0 = bm * 64 + wave * 16;    // flat row in [0,4096)
  const int n0 = bn * 16;
  const int token = p.tok[m0 + arow];
  const float* A = p.emb + (size_t)token * 512;
  const unsigned short* Bp = p.W0E + (size_t)(n0 + arow) * 512 + kq;
  f32x4 acc = zero4();
  for (int kk = 0; kk < 512; kk += 32) {
    bf16x8 ah, al;
    splitA(A + kk + kq, ah, al);
    acc = mfma3(ah, al, ldb(Bp + kk), ldb(Bp + NW0E + kk), acc);
  }
  const int r0 = m0 + (lane >> 4) * 4;
  const float bb = p.b0[n0 + arow];
#pragma unroll
  for (int r = 0; r < 4; ++r)
    p.EGb[(size_t)(r0 + r) * 2048 + n0 + arow] = acc[r] + bb;
}

// ---------------- persistent decoder: 256 WGs x 256 threads ----------------
__global__ void __launch_bounds__(256) decoder_main(P p) {
  const int wg = blockIdx.x, tid = threadIdx.x;
  const int wave = tid >> 6, lane = tid & 63;
  const int arow = lane & 15;            // fragment row (A: m, B: n)
  const int kq = (lane >> 4) * 8;
  unsigned* gctr = p.flag + 64;
  unsigned bt = 0;

  __shared__ float MwL[32][512];          // 64 KB, pinned: Mw quarter (f32)
  __shared__ float Aslab[16][516];        // 33 KB, staged GEMM A operand
  __shared__ float exch[4][16][16];       // gate exchange
  __shared__ float scl[128];
  __shared__ float pl[128];

  const int attb = wg >> 2, attq = wg & 3;
  // pin score-matrix LDS (prep output; coherent at kernel launch)
  for (int idx = tid; idx < 32 * 512; idx += 256) {
    int r = idx >> 9, c = idx & 511;
    MwL[r][c] = p.Mw[(size_t)(attb * 128 + attq * 32 + r) * 512 + c];
  }

  const int w2 = (wg < 128) ? wg : wg - 128;
  const int strip = w2 & 31;             // 16-col strip within a gate (512/16)
  const int mblk = w2 >> 5;              // 16-row batch block (64/16)
  const int gate = wave;                 // wave-per-gate
  const int colj = strip * 16 + arow;

  auto stage = [&](const float* base) {  // [16][512] row-major -> Aslab
    __syncthreads();
    for (int idx = tid * 4; idx < 16 * 512; idx += 1024) {
      int r = idx >> 9, c = idx & 511;
      float4 v = *(const float4*)(base + r * 512 + c);
      *(float4*)&Aslab[r][c] = v;
    }
    __syncthreads();
  };
  auto gemm_half = [&](const unsigned short* whi, const unsigned short* wlo,
                       f32x4 acc) {
#pragma unroll 4
    for (int kk = 0; kk < 512; kk += 32) {
      bf16x8 ah, al;
      splitA(&Aslab[arow][kk + kq], ah, al);
      acc = mfma3(ah, al, ldb(whi + kk), ldb(wlo + kk), acc);
    }
    return acc;
  };

  for (int t = 0; t < TT; ++t) {
    const float* h0c = p.h0buf + (t & 1) * (BB * HH);
    float* h0n = p.h0buf + ((t + 1) & 1) * (BB * HH);

    // ---- P1: gates0+cell0 (wg<128) || h1_prev @ Whh1 + b1 (wg>=128) ----
    if (wg < 128) {
      const size_t wr = (size_t)(gate * 512 + colj) * 1024;
      f32x4 acc = zero4();
      stage(p.feed + mblk * 16 * 512);
      acc = gemm_half(p.W0R + wr + kq, p.W0R + NW0R + wr + kq, acc);
      stage(h0c + mblk * 16 * 512);
      acc = gemm_half(p.W0R + wr + 512 + kq, p.W0R + NW0R + wr + 512 + kq, acc);
      const float* eg =
          p.EGb + ((size_t)(t * 64 + mblk * 16)) * 2048 + gate * 512 + colj;
#pragma unroll
      for (int r = 0; r < 4; ++r) {
        acc[r] += eg[((lane >> 4) * 4 + r) * 2048];
        exch[gate][(lane >> 4) * 4 + r][arow] = acc[r];
      }
      __syncthreads();
      {
        int br = tid >> 4, nc = tid & 15;
        int idx = (mblk * 16 + br) * 512 + strip * 16 + nc;
        float iv = sigm(exch[0][br][nc]);
        float fv = sigm(exch[1][br][nc]);
        float gv = tanhf(exch[2][br][nc]);
        float ov = sigm(exch[3][br][nc]);
        float cn = fv * p.c0s[idx] + iv * gv;
        p.c0s[idx] = cn;
        h0n[idx] = ov * tanhf(cn);
      }
    } else {
      const size_t wr = (size_t)(gate * 512 + colj) * 512;
      stage(p.h1s + mblk * 16 * 512);
      f32x4 acc = gemm_half(p.Whh1 + wr + kq, p.Whh1 + NW1 + wr + kq, zero4());
      const float bb = p.b1[gate * 512 + colj];
#pragma unroll
      for (int r = 0; r < 4; ++r)
        p.part1[(mblk * 16 + (lane >> 4) * 4 + r) * 2048 + gate * 512 + colj] =
            acc[r] + bb;
    }
    bt += 256; gbar(gctr, bt);

    // ---- P2: gates1(ih part) + part1 + cell1 (wg<128); ctx zero (128..159) ----
    if (wg < 128) {
      const size_t wr = (size_t)(gate * 512 + colj) * 512;
      stage(h0n + mblk * 16 * 512);
      f32x4 acc = gemm_half(p.Wih1 + wr + kq, p.Wih1 + NW1 + wr + kq, zero4());
#pragma unroll
      for (int r = 0; r < 4; ++r) {
        acc[r] += p.part1[(mblk * 16 + (lane >> 4) * 4 + r) * 2048 +
                          gate * 512 + colj];
        exch[gate][(lane >> 4) * 4 + r][arow] = acc[r];
      }
      __syncthreads();
      {
        int br = tid >> 4, nc = tid & 15;
        int idx = (mblk * 16 + br) * 512 + strip * 16 + nc;
        float iv = sigm(exch[0][br][nc]);
        float fv = sigm(exch[1][br][nc]);
        float gv = tanhf(exch[2][br][nc]);
        float ov = sigm(exch[3][br][nc]);
        float cn = fv * p.c1s[idx] + iv * gv;
        p.c1s[idx] = cn;
        p.h1s[idx] = ov * tanhf(cn);
      }
    } else if (wg < 160) {
      int base = (wg - 128) * 1024 + tid * 4;
#pragma unroll
      for (int i = 0; i < 4; ++i)
        __hip_atomic_store(&p.ctx[base + i], 0.f, __ATOMIC_RELAXED,
                           __HIP_MEMORY_SCOPE_AGENT);
    }
    bt += 256; gbar(gctr, bt);

    // ---- P3: attention (4 WGs per batch; scores from LDS Mw, ctx from f32 mbank) ----
    {
      float h8[8];
      {
        float4 a = *(const float4*)(p.h1s + attb * 512 + lane * 8);
        float4 c = *(const float4*)(p.h1s + attb * 512 + lane * 8 + 4);
        h8[0] = a.x; h8[1] = a.y; h8[2] = a.z; h8[3] = a.w;
        h8[4] = c.x; h8[5] = c.y; h8[6] = c.z; h8[7] = c.w;
      }
#pragma unroll
      for (int i = 0; i < 8; ++i) {
        const int sl = wave * 8 + i;
        const float* mw = &MwL[sl][lane * 8];
        float d = h8[0] * mw[0] + h8[1] * mw[1] + h8[2] * mw[2] + h8[3] * mw[3] +
                  h8[4] * mw[4] + h8[5] * mw[5] + h8[6] * mw[6] + h8[7] * mw[7];
#pragma unroll
        for (int o = 32; o; o >>= 1) d += __shfl_xor(d, o);
        if (lane == 0)
          __hip_atomic_store(&p.scg[attb * 128 + attq * 32 + sl], d,
                             __ATOMIC_RELAXED, __HIP_MEMORY_SCOPE_AGENT);
      }
      __syncthreads();                   // drains the score stores (vmcnt 0)
      if (tid == 0) {
        __hip_atomic_fetch_add(&p.flag[attb], 1u, __ATOMIC_RELAXED,
                               __HIP_MEMORY_SCOPE_AGENT);
        const unsigned tgt = 4u * (unsigned)(t + 1);
        while (__hip_atomic_load(&p.flag[attb], __ATOMIC_RELAXED,
                                 __HIP_MEMORY_SCOPE_AGENT) < tgt)
          __builtin_amdgcn_s_sleep(2);
      }
      __syncthreads();
      if (tid < 128)
        scl[tid] = __hip_atomic_load(&p.scg[attb * 128 + tid], __ATOMIC_RELAXED,
                                     __HIP_MEMORY_SCOPE_AGENT);
      __syncthreads();
      if (wave == 0) {
        const int lenb = p.len[attb];
        float s0 = (lane < lenb) ? scl[lane] : -__builtin_inff();
        float s1 = (lane + 64 < lenb) ? scl[lane + 64] : -__builtin_inff();
        float mx = fmaxf(s0, s1);
#pragma unroll
        for (int o = 32; o; o >>= 1) mx = fmaxf(mx, __shfl_xor(mx, o));
        float e0 = (lane < lenb) ? __expf(s0 - mx) : 0.f;
        float e1 = (lane + 64 < lenb) ? __expf(s1 - mx) : 0.f;
        float sm = e0 + e1;
#pragma unroll
        for (int o = 32; o; o >>= 1) sm += __shfl_xor(sm, o);
        float inv = 1.f / sm;
        pl[lane] = e0 * inv; pl[lane + 64] = e1 * inv;
        if (attq == 0) {
          float* ao = p.out_attn + ((size_t)t * BB + attb) * SS;
          ao[lane] = e0 * inv; ao[lane + 64] = e1 * inv;
        }
      }
      __syncthreads();
      {
        const float* MbB = p.mbank + (size_t)(attb * 128 + attq * 32) * 512;
        const int h2 = tid * 2;
        float ca = 0.f, cb = 0.f;
#pragma unroll 4
        for (int s = 0; s < 32; ++s) {
          float ps = pl[attq * 32 + s];
          float2 v = *(const float2*)(MbB + (size_t)s * 512 + h2);
          ca += ps * v.x;
          cb += ps * v.y;
        }
        atomicAdd(&p.ctx[attb * 512 + h2], ca);
        atomicAdd(&p.ctx[attb * 512 + h2 + 1], cb);
      }
    }
    bt += 256; gbar(gctr, bt);

    // ---- P4: attn_h = tanh([ctx | h1] @ Wout^T) -> out_dec, feed ----
    if (wg < 32) {
      const int m4 = wg >> 3, ngrp = wg & 7;
      const int nstrip = ngrp * 4 + wave;
      const int cj = nstrip * 16 + arow;
      const size_t wr = (size_t)cj * 1024;
      f32x4 acc = zero4();
      stage(p.ctx + m4 * 16 * 512);
      acc = gemm_half(p.Wout + wr + kq, p.Wout + NWO + wr + kq, acc);
      stage(p.h1s + m4 * 16 * 512);
      acc = gemm_half(p.Wout + wr + 512 + kq, p.Wout + NWO + wr + 512 + kq, acc);
      float* dec = p.out_dec + (size_t)t * BB * HH;
#pragma unroll
      for (int r = 0; r < 4; ++r) {
        int b = m4 * 16 + (lane >> 4) * 4 + r;
        float v = tanhf(acc[r]);
        dec[b * 512 + cj] = v;
        p.feed[b * 512 + cj] = v;
      }
    }
    bt += 256; gbar(gctr, bt);
  }

  // ---- final states ----
  for (int i = wg * 256 + tid; i < BB * HH; i += 256 * 256) {
    p.out_hf[i] = p.h0buf[i];            // TT even -> buffer 0
    p.out_hf[BB * HH + i] = p.h1s[i];
    p.out_cf[i] = p.c0s[i];
    p.out_cf[BB * HH + i] = p.c1s[i];
  }
}

extern "C" void kernel_launch(void* const* d_in, const int* in_sizes, int n_in,
                              void* d_out, int out_size, void* d_ws, size_t ws_size,
                              hipStream_t stream) {
  P p;
  p.tok   = (const int*)d_in[0];
  p.mbank = (const float*)d_in[1];
  p.len   = (const int*)d_in[2];
  p.h0_in = (const float*)d_in[3];
  p.c0_in = (const float*)d_in[4];
  p.emb   = (const float*)d_in[5];
  p.w_ih0 = (const float*)d_in[6];
  p.w_hh0 = (const float*)d_in[7];
  p.b_ih0 = (const float*)d_in[8];
  p.b_hh0 = (const float*)d_in[9];
  p.w_ih1 = (const float*)d_in[10];
  p.w_hh1 = (const float*)d_in[11];
  p.b_ih1 = (const float*)d_in[12];
  p.b_hh1 = (const float*)d_in[13];
  p.w_in  = (const float*)d_in[14];
  p.w_out = (const float*)d_in[15];

  float* out = (float*)d_out;
  p.out_dec  = out;
  p.out_attn = out + (size_t)TT * BB * HH;
  p.out_hf   = out + (size_t)TT * BB * HH + (size_t)TT * BB * SS;
  p.out_cf   = p.out_hf + 2 * BB * HH;

  char* w = (char*)d_ws;
  auto alloc = [&](size_t n) { char* r = w; w += (n + 255) & ~(size_t)255; return r; };
  p.W0E   = (unsigned short*)alloc((size_t)NW0E * 2 * 2);
  p.W0R   = (unsigned short*)alloc((size_t)NW0R * 2 * 2);
  p.Wih1  = (unsigned short*)alloc((size_t)NW1 * 2 * 2);
  p.Whh1  = (unsigned short*)alloc((size_t)NW1 * 2 * 2);
  p.Wout  = (unsigned short*)alloc((size_t)NWO * 2 * 2);
  p.WinT  = (unsigned short*)alloc((size_t)NWI * 2 * 2);
  p.EGb   = (float*)alloc((size_t)4096 * 2048 * 4);
  p.Mw    = (float*)alloc((size_t)BB * SS * HH * 4);
  p.b0    = (float*)alloc(2048 * 4);
  p.b1    = (float*)alloc(2048 * 4);
  p.h0buf = (float*)alloc((size_t)2 * BB * HH * 4);
  p.h1s   = (float*)alloc((size_t)BB * HH * 4);
  p.c0s   = (float*)alloc((size_t)BB * HH * 4);
  p.c1s   = (float*)alloc((size_t)BB * HH * 4);
  p.feed  = (float*)alloc((size_t)BB * HH * 4);
  p.part1 = (float*)alloc((size_t)BB * GG * 4);
  p.ctx   = (float*)alloc((size_t)BB * HH * 4);
  p.scg   = (float*)alloc((size_t)BB * SS * 4);
  p.flag  = (unsigned int*)alloc(128 * 4);

  hipLaunchKernelGGL(prep_weights, dim3(4096), dim3(256), 0, stream, p);
  hipLaunchKernelGGL(prep_mw, dim3(4096), dim3(256), 0, stream, p);
  hipLaunchKernelGGL(prep_eg, dim3(8192), dim3(256), 0, stream, p);
  void* args[] = {(void*)&p};
  hipLaunchCooperativeKernel((void*)decoder_main, dim3(256), dim3(256), args, 0, stream);
}

// Round 7
// 4981.584 us; speedup vs baseline: 2.6243x; 1.7680x over previous
//
#include <hip/hip_runtime.h>
#include <hip/hip_bf16.h>

typedef __bf16 bf16x8 __attribute__((ext_vector_type(8)));
typedef unsigned short u16x8 __attribute__((ext_vector_type(8)));
typedef float f32x4 __attribute__((ext_vector_type(4)));

constexpr int TT = 64;   // timesteps
constexpr int BB = 64;   // batch
constexpr int SS = 128;  // memory length
constexpr int HH = 512;  // hidden
constexpr int GG = 2048; // 4*H

// weight sizes (elements); hi at [0], lo at [N]
constexpr int NW0E = 2048 * 512;
constexpr int NW0R = 2048 * 1024;
constexpr int NW1  = 2048 * 512;
constexpr int NWO  = 512 * 1024;
constexpr int NWI  = 512 * 512;

struct P {
  const int* tok; const float* mbank; const int* len;
  const float* h0_in; const float* c0_in; const float* emb;
  const float* w_ih0; const float* w_hh0; const float* b_ih0; const float* b_hh0;
  const float* w_ih1; const float* w_hh1; const float* b_ih1; const float* b_hh1;
  const float* w_in; const float* w_out;
  float* out_dec; float* out_attn; float* out_hf; float* out_cf;
  unsigned short *W0E, *W0R, *Wih1, *Whh1, *Wout, *WinT;
  float *EGb;                             // f32: score-path precision
  float *Mw;
  float *b0, *b1, *h0buf, *h1s, *c0s, *c1s, *feed, *part1, *ctx, *scg;
  unsigned int* flag;                     // [0..63] P3 groups, [64] grid barrier
};

__device__ __forceinline__ unsigned short f2bf(float f) {
  unsigned int u = __builtin_bit_cast(unsigned int, f);
  return (unsigned short)((u + 0x7fffu + ((u >> 16) & 1u)) >> 16);
}
__device__ __forceinline__ float bf2f(unsigned short h) {
  return __builtin_bit_cast(float, ((unsigned int)h) << 16);
}
__device__ __forceinline__ bf16x8 ldb(const unsigned short* p) {
  return __builtin_bit_cast(bf16x8, *(const u16x8*)p);
}
__device__ __forceinline__ f32x4 mfma_(bf16x8 a, bf16x8 b, f32x4 c) {
  return __builtin_amdgcn_mfma_f32_16x16x32_bf16(a, b, c, 0, 0, 0);
}
__device__ __forceinline__ float sigm(float x) { return 1.f / (1.f + __expf(-x)); }
__device__ __forceinline__ f32x4 zero4() { f32x4 z = {0.f, 0.f, 0.f, 0.f}; return z; }

#define ATL(pp) __hip_atomic_load((pp), __ATOMIC_RELAXED, __HIP_MEMORY_SCOPE_AGENT)
#define ATS(pp, vv) __hip_atomic_store((pp), (vv), __ATOMIC_RELAXED, __HIP_MEMORY_SCOPE_AGENT)

// ---- fence-free grid barrier: relaxed LLC counter; NO cache invalidation ----
__device__ __forceinline__ void gbar(unsigned* ctr, unsigned target) {
  asm volatile("s_waitcnt vmcnt(0)" ::: "memory");   // drain this wave's stores
  __syncthreads();
  if (threadIdx.x == 0) {
    __hip_atomic_fetch_add(ctr, 1u, __ATOMIC_RELAXED, __HIP_MEMORY_SCOPE_AGENT);
    while (__hip_atomic_load(ctr, __ATOMIC_RELAXED, __HIP_MEMORY_SCOPE_AGENT) < target)
      __builtin_amdgcn_s_sleep(1);
  }
  __syncthreads();
}

__device__ __forceinline__ void splitA(const float* s, bf16x8& hi, bf16x8& lo) {
  float4 a0 = *(const float4*)s;
  float4 a1 = *(const float4*)(s + 4);
  float v[8] = {a0.x, a0.y, a0.z, a0.w, a1.x, a1.y, a1.z, a1.w};
  u16x8 h, l;
#pragma unroll
  for (int j = 0; j < 8; ++j) {
    unsigned short hb = f2bf(v[j]);
    h[j] = hb;
    l[j] = f2bf(v[j] - bf2f(hb));
  }
  hi = __builtin_bit_cast(bf16x8, h);
  lo = __builtin_bit_cast(bf16x8, l);
}
__device__ __forceinline__ f32x4 mfma3(bf16x8 ah, bf16x8 al, bf16x8 bh, bf16x8 bl, f32x4 c) {
  c = mfma_(al, bh, c);
  c = mfma_(ah, bl, c);
  c = mfma_(ah, bh, c);
  return c;
}

// ---------------- prep: weight split / transpose / state init ----------------
__global__ void prep_weights(P p) {
  constexpr int TOT = NW0E + NW0R + NW1 + NW1 + NWO + NWI + 2048 + 2048 +
                      32768 * 5 + 8192 + 128;
  for (int i = blockIdx.x * blockDim.x + threadIdx.x; i < TOT;
       i += gridDim.x * blockDim.x) {
    int j = i;
    float v; unsigned short* dst; int N;
    if (j < NW0E) {              // emb part of w_ih0: [2048][512]
      int n = j >> 9, k = j & 511;
      v = p.w_ih0[n * 1024 + k];
      dst = p.W0E; N = NW0E; goto split;
    }
    j -= NW0E;
    if (j < NW0R) {              // [feed | h] : [2048][1024]
      int n = j >> 10, k = j & 1023;
      v = (k < 512) ? p.w_ih0[n * 1024 + 512 + k] : p.w_hh0[n * 512 + (k - 512)];
      dst = p.W0R; N = NW0R; goto split;
    }
    j -= NW0R;
    if (j < NW1) { v = p.w_ih1[j]; dst = p.Wih1; N = NW1; goto split; }
    j -= NW1;
    if (j < NW1) { v = p.w_hh1[j]; dst = p.Whh1; N = NW1; goto split; }
    j -= NW1;
    if (j < NWO) { v = p.w_out[j]; dst = p.Wout; N = NWO; goto split; }
    j -= NWO;
    if (j < NWI) {               // WinT[n][k] = w_in[k][n]
      int n = j >> 9, q = j & 511;
      v = p.w_in[q * 512 + n];
      dst = p.WinT; N = NWI; goto split;
    }
    j -= NWI;
    if (j < 2048) { p.b0[j] = p.b_ih0[j] + p.b_hh0[j]; continue; }
    j -= 2048;
    if (j < 2048) { p.b1[j] = p.b_ih1[j] + p.b_hh1[j]; continue; }
    j -= 2048;
    if (j < 32768) { p.h0buf[j] = p.h0_in[j]; continue; }
    j -= 32768;
    if (j < 32768) { p.h1s[j] = p.h0_in[32768 + j]; continue; }
    j -= 32768;
    if (j < 32768) { p.c0s[j] = p.c0_in[j]; continue; }
    j -= 32768;
    if (j < 32768) { p.c1s[j] = p.c0_in[32768 + j]; continue; }
    j -= 32768;
    if (j < 32768) { p.feed[j] = 0.f; continue; }
    j -= 32768;
    if (j < 8192) { p.scg[j] = 0.f; continue; }
    j -= 8192;
    p.flag[j] = 0u;
    continue;
  split:
    {
      unsigned short hb = f2bf(v);
      dst[j] = hb;
      dst[N + j] = f2bf(v - bf2f(hb));
    }
  }
}

// ---------------- prep: Mw[b,s,n] = sum_k M[b,s,k] * w_in[k,n]  (f32) ----------------
__global__ void prep_mw(P p) {
  const int wg = blockIdx.x;             // 4096 = 128 m-blocks x 32 n-tiles
  const int bm = wg & 127, bn = wg >> 7;
  const int tid = threadIdx.x, wave = tid >> 6, lane = tid & 63;
  const int arow = lane & 15, kq = (lane >> 4) * 8;
  const int m0 = bm * 64 + wave * 16;
  const int n0 = bn * 16;
  const float* A = p.mbank + (size_t)(m0 + arow) * HH;
  const unsigned short* Bp = p.WinT + (size_t)(n0 + arow) * HH + kq;
  f32x4 acc = zero4();
  for (int kk = 0; kk < HH; kk += 32) {
    bf16x8 ah, al;
    splitA(A + kk + kq, ah, al);
    acc = mfma3(ah, al, ldb(Bp + kk), ldb(Bp + NWI + kk), acc);
  }
  const int r0 = m0 + (lane >> 4) * 4;
#pragma unroll
  for (int r = 0; r < 4; ++r)
    p.Mw[(size_t)(r0 + r) * HH + n0 + arow] = acc[r];
}

// ---------------- prep: EGb[t*64+b, n] = emb[tok] @ W0E^T + b0  (f32) ----------------
__global__ void prep_eg(P p) {
  const int wg = blockIdx.x;             // 8192 = 64 m-blocks x 128 n-tiles
  const int bn = wg & 127, bm = wg >> 7;
  const int tid = threadIdx.x, wave = tid >> 6, lane = tid & 63;
  const int arow = lane & 15, kq = (lane >> 4) * 8;
  const int m0 = bm * 64 + wave * 16;    // flat row in [0,4096)
  const int n0 = bn * 16;
  const int token = p.tok[m0 + arow];
  const float* A = p.emb + (size_t)token * 512;
  const unsigned short* Bp = p.W0E + (size_t)(n0 + arow) * 512 + kq;
  f32x4 acc = zero4();
  for (int kk = 0; kk < 512; kk += 32) {
    bf16x8 ah, al;
    splitA(A + kk + kq, ah, al);
    acc = mfma3(ah, al, ldb(Bp + kk), ldb(Bp + NW0E + kk), acc);
  }
  const int r0 = m0 + (lane >> 4) * 4;
  const float bb = p.b0[n0 + arow];
#pragma unroll
  for (int r = 0; r < 4; ++r)
    p.EGb[(size_t)(r0 + r) * 2048 + n0 + arow] = acc[r] + bb;
}

// ---------------- persistent decoder: 256 WGs x 256 threads ----------------
__global__ void __launch_bounds__(256) decoder_main(P p) {
  const int wg = blockIdx.x, tid = threadIdx.x;
  const int wave = tid >> 6, lane = tid & 63;
  const int arow = lane & 15;            // fragment row (A: m, B: n)
  const int kq = (lane >> 4) * 8;
  unsigned* gctr = p.flag + 64;
  unsigned bt = 0;

  __shared__ float MwL[32][512];          // 64 KB, pinned: Mw quarter (f32)
  __shared__ float Aslab[16][516];        // 33 KB, staged GEMM A operand
  __shared__ float exch[4][16][16];       // gate exchange
  __shared__ float scl[128];
  __shared__ float pl[128];

  const int attb = wg >> 2, attq = wg & 3;
  // pin score-matrix LDS (prep output; coherent at kernel launch)
  for (int idx = tid; idx < 32 * 512; idx += 256) {
    int r = idx >> 9, c = idx & 511;
    MwL[r][c] = p.Mw[(size_t)(attb * 128 + attq * 32 + r) * 512 + c];
  }

  const int w2 = (wg < 128) ? wg : wg - 128;
  const int strip = w2 & 31;             // 16-col strip within a gate (512/16)
  const int mblk = w2 >> 5;              // 16-row batch block (64/16)
  const int gate = wave;                 // wave-per-gate
  const int colj = strip * 16 + arow;

  // coherent stage: LLC (sc0 sc1) loads bypass stale L2; weights stay cached
  auto stageC = [&](const float* base) { // [16][512] row-major -> Aslab
    __syncthreads();
    float4 v[8];
    const float* ap[8];
#pragma unroll
    for (int j = 0; j < 8; ++j) {
      int idx = tid * 4 + j * 1024;
      ap[j] = base + (idx >> 9) * 512 + (idx & 511);
    }
#pragma unroll
    for (int j = 0; j < 8; ++j)
      asm volatile("global_load_dwordx4 %0, %1, off sc0 sc1"
                   : "=v"(v[j]) : "v"(ap[j]));
    asm volatile("s_waitcnt vmcnt(0)" ::: "memory");
    __builtin_amdgcn_sched_barrier(0);
#pragma unroll
    for (int j = 0; j < 8; ++j) {
      int idx = tid * 4 + j * 1024;
      *(float4*)&Aslab[idx >> 9][idx & 511] = v[j];
    }
    __syncthreads();
  };
  auto gemm_half = [&](const unsigned short* whi, const unsigned short* wlo,
                       f32x4 acc) {
#pragma unroll 4
    for (int kk = 0; kk < 512; kk += 32) {
      bf16x8 ah, al;
      splitA(&Aslab[arow][kk + kq], ah, al);
      acc = mfma3(ah, al, ldb(whi + kk), ldb(wlo + kk), acc);
    }
    return acc;
  };

  for (int t = 0; t < TT; ++t) {
    const float* h0c = p.h0buf + (t & 1) * (BB * HH);
    float* h0n = p.h0buf + ((t + 1) & 1) * (BB * HH);

    // ---- P1: gates0+cell0 (wg<128) || h1_prev @ Whh1 + b1 (wg>=128) ----
    if (wg < 128) {
      const size_t wr = (size_t)(gate * 512 + colj) * 1024;
      f32x4 acc = zero4();
      stageC(p.feed + mblk * 16 * 512);
      acc = gemm_half(p.W0R + wr + kq, p.W0R + NW0R + wr + kq, acc);
      stageC(h0c + mblk * 16 * 512);
      acc = gemm_half(p.W0R + wr + 512 + kq, p.W0R + NW0R + wr + 512 + kq, acc);
      const float* eg =
          p.EGb + ((size_t)(t * 64 + mblk * 16)) * 2048 + gate * 512 + colj;
#pragma unroll
      for (int r = 0; r < 4; ++r) {
        acc[r] += eg[((lane >> 4) * 4 + r) * 2048];
        exch[gate][(lane >> 4) * 4 + r][arow] = acc[r];
      }
      __syncthreads();
      {
        int br = tid >> 4, nc = tid & 15;
        int idx = (mblk * 16 + br) * 512 + strip * 16 + nc;
        float iv = sigm(exch[0][br][nc]);
        float fv = sigm(exch[1][br][nc]);
        float gv = tanhf(exch[2][br][nc]);
        float ov = sigm(exch[3][br][nc]);
        float cn = fv * p.c0s[idx] + iv * gv;   // c0s: WG-private, plain
        p.c0s[idx] = cn;
        float hv = ov * tanhf(cn);
        ATS(&h0n[idx], hv);
        if (t == TT - 1) { p.out_cf[idx] = cn; p.out_hf[idx] = hv; }
      }
    } else {
      const size_t wr = (size_t)(gate * 512 + colj) * 512;
      stageC(p.h1s + mblk * 16 * 512);
      f32x4 acc = gemm_half(p.Whh1 + wr + kq, p.Whh1 + NW1 + wr + kq, zero4());
      const float bb = p.b1[gate * 512 + colj];
#pragma unroll
      for (int r = 0; r < 4; ++r)
        ATS(&p.part1[(mblk * 16 + (lane >> 4) * 4 + r) * 2048 + gate * 512 + colj],
            acc[r] + bb);
    }
    bt += 256; gbar(gctr, bt);

    // ---- P2: gates1(ih part) + part1 + cell1 (wg<128); ctx zero (128..159) ----
    if (wg < 128) {
      const size_t wr = (size_t)(gate * 512 + colj) * 512;
      stageC(h0n + mblk * 16 * 512);
      f32x4 acc = gemm_half(p.Wih1 + wr + kq, p.Wih1 + NW1 + wr + kq, zero4());
#pragma unroll
      for (int r = 0; r < 4; ++r) {
        acc[r] += ATL(&p.part1[(mblk * 16 + (lane >> 4) * 4 + r) * 2048 +
                               gate * 512 + colj]);
        exch[gate][(lane >> 4) * 4 + r][arow] = acc[r];
      }
      __syncthreads();
      {
        int br = tid >> 4, nc = tid & 15;
        int idx = (mblk * 16 + br) * 512 + strip * 16 + nc;
        float iv = sigm(exch[0][br][nc]);
        float fv = sigm(exch[1][br][nc]);
        float gv = tanhf(exch[2][br][nc]);
        float ov = sigm(exch[3][br][nc]);
        float cn = fv * p.c1s[idx] + iv * gv;   // c1s: WG-private, plain
        p.c1s[idx] = cn;
        float hv = ov * tanhf(cn);
        ATS(&p.h1s[idx], hv);
        if (t == TT - 1) { p.out_cf[BB * HH + idx] = cn; p.out_hf[BB * HH + idx] = hv; }
      }
    } else if (wg < 160) {
      int base = (wg - 128) * 1024 + tid * 4;
#pragma unroll
      for (int i = 0; i < 4; ++i) ATS(&p.ctx[base + i], 0.f);
    }
    bt += 256; gbar(gctr, bt);

    // ---- P3: attention (4 WGs per batch; scores from LDS Mw, ctx from f32 mbank) ----
    {
      float h8[8];
      {
        const float* hp = p.h1s + attb * 512 + lane * 8;
        float4 a, c;
        asm volatile("global_load_dwordx4 %0, %1, off sc0 sc1" : "=v"(a) : "v"(hp));
        asm volatile("global_load_dwordx4 %0, %1, off sc0 sc1" : "=v"(c) : "v"(hp + 4));
        asm volatile("s_waitcnt vmcnt(0)" ::: "memory");
        __builtin_amdgcn_sched_barrier(0);
        h8[0] = a.x; h8[1] = a.y; h8[2] = a.z; h8[3] = a.w;
        h8[4] = c.x; h8[5] = c.y; h8[6] = c.z; h8[7] = c.w;
      }
#pragma unroll
      for (int i = 0; i < 8; ++i) {
        const int sl = wave * 8 + i;
        const float* mw = &MwL[sl][lane * 8];
        float d = h8[0] * mw[0] + h8[1] * mw[1] + h8[2] * mw[2] + h8[3] * mw[3] +
                  h8[4] * mw[4] + h8[5] * mw[5] + h8[6] * mw[6] + h8[7] * mw[7];
#pragma unroll
        for (int o = 32; o; o >>= 1) d += __shfl_xor(d, o);
        if (lane == 0) ATS(&p.scg[attb * 128 + attq * 32 + sl], d);
      }
      asm volatile("s_waitcnt vmcnt(0)" ::: "memory");
      __syncthreads();                   // all score stores drained
      if (tid == 0) {
        __hip_atomic_fetch_add(&p.flag[attb], 1u, __ATOMIC_RELAXED,
                               __HIP_MEMORY_SCOPE_AGENT);
        const unsigned tgt = 4u * (unsigned)(t + 1);
        while (__hip_atomic_load(&p.flag[attb], __ATOMIC_RELAXED,
                                 __HIP_MEMORY_SCOPE_AGENT) < tgt)
          __builtin_amdgcn_s_sleep(1);
      }
      __syncthreads();
      if (tid < 128) scl[tid] = ATL(&p.scg[attb * 128 + tid]);
      __syncthreads();
      if (wave == 0) {
        const int lenb = p.len[attb];
        float s0 = (lane < lenb) ? scl[lane] : -__builtin_inff();
        float s1 = (lane + 64 < lenb) ? scl[lane + 64] : -__builtin_inff();
        float mx = fmaxf(s0, s1);
#pragma unroll
        for (int o = 32; o; o >>= 1) mx = fmaxf(mx, __shfl_xor(mx, o));
        float e0 = (lane < lenb) ? __expf(s0 - mx) : 0.f;
        float e1 = (lane + 64 < lenb) ? __expf(s1 - mx) : 0.f;
        float sm = e0 + e1;
#pragma unroll
        for (int o = 32; o; o >>= 1) sm += __shfl_xor(sm, o);
        float inv = 1.f / sm;
        pl[lane] = e0 * inv; pl[lane + 64] = e1 * inv;
        if (attq == 0) {
          float* ao = p.out_attn + ((size_t)t * BB + attb) * SS;
          ao[lane] = e0 * inv; ao[lane + 64] = e1 * inv;
        }
      }
      __syncthreads();
      {
        const float* MbB = p.mbank + (size_t)(attb * 128 + attq * 32) * 512;
        const int h2 = tid * 2;
        float ca = 0.f, cb = 0.f;
#pragma unroll 4
        for (int s = 0; s < 32; ++s) {
          float ps = pl[attq * 32 + s];
          float2 v = *(const float2*)(MbB + (size_t)s * 512 + h2);
          ca += ps * v.x;
          cb += ps * v.y;
        }
        atomicAdd(&p.ctx[attb * 512 + h2], ca);
        atomicAdd(&p.ctx[attb * 512 + h2 + 1], cb);
      }
    }
    bt += 256; gbar(gctr, bt);

    // ---- P4: attn_h = tanh([ctx | h1] @ Wout^T) -> out_dec, feed ----
    if (wg < 32) {
      const int m4 = wg >> 3, ngrp = wg & 7;
      const int nstrip = ngrp * 4 + wave;
      const int cj = nstrip * 16 + arow;
      const size_t wr = (size_t)cj * 1024;
      f32x4 acc = zero4();
      stageC(p.ctx + m4 * 16 * 512);
      acc = gemm_half(p.Wout + wr + kq, p.Wout + NWO + wr + kq, acc);
      stageC(p.h1s + m4 * 16 * 512);
      acc = gemm_half(p.Wout + wr + 512 + kq, p.Wout + NWO + wr + 512 + kq, acc);
      float* dec = p.out_dec + (size_t)t * BB * HH;
#pragma unroll
      for (int r = 0; r < 4; ++r) {
        int b = m4 * 16 + (lane >> 4) * 4 + r;
        float v = tanhf(acc[r]);
        dec[b * 512 + cj] = v;
        ATS(&p.feed[b * 512 + cj], v);
      }
    }
    bt += 256; gbar(gctr, bt);
  }
}

extern "C" void kernel_launch(void* const* d_in, const int* in_sizes, int n_in,
                              void* d_out, int out_size, void* d_ws, size_t ws_size,
                              hipStream_t stream) {
  P p;
  p.tok   = (const int*)d_in[0];
  p.mbank = (const float*)d_in[1];
  p.len   = (const int*)d_in[2];
  p.h0_in = (const float*)d_in[3];
  p.c0_in = (const float*)d_in[4];
  p.emb   = (const float*)d_in[5];
  p.w_ih0 = (const float*)d_in[6];
  p.w_hh0 = (const float*)d_in[7];
  p.b_ih0 = (const float*)d_in[8];
  p.b_hh0 = (const float*)d_in[9];
  p.w_ih1 = (const float*)d_in[10];
  p.w_hh1 = (const float*)d_in[11];
  p.b_ih1 = (const float*)d_in[12];
  p.b_hh1 = (const float*)d_in[13];
  p.w_in  = (const float*)d_in[14];
  p.w_out = (const float*)d_in[15];

  float* out = (float*)d_out;
  p.out_dec  = out;
  p.out_attn = out + (size_t)TT * BB * HH;
  p.out_hf   = out + (size_t)TT * BB * HH + (size_t)TT * BB * SS;
  p.out_cf   = p.out_hf + 2 * BB * HH;

  char* w = (char*)d_ws;
  auto alloc = [&](size_t n) { char* r = w; w += (n + 255) & ~(size_t)255; return r; };
  p.W0E   = (unsigned short*)alloc((size_t)NW0E * 2 * 2);
  p.W0R   = (unsigned short*)alloc((size_t)NW0R * 2 * 2);
  p.Wih1  = (unsigned short*)alloc((size_t)NW1 * 2 * 2);
  p.Whh1  = (unsigned short*)alloc((size_t)NW1 * 2 * 2);
  p.Wout  = (unsigned short*)alloc((size_t)NWO * 2 * 2);
  p.WinT  = (unsigned short*)alloc((size_t)NWI * 2 * 2);
  p.EGb   = (float*)alloc((size_t)4096 * 2048 * 4);
  p.Mw    = (float*)alloc((size_t)BB * SS * HH * 4);
  p.b0    = (float*)alloc(2048 * 4);
  p.b1    = (float*)alloc(2048 * 4);
  p.h0buf = (float*)alloc((size_t)2 * BB * HH * 4);
  p.h1s   = (float*)alloc((size_t)BB * HH * 4);
  p.c0s   = (float*)alloc((size_t)BB * HH * 4);
  p.c1s   = (float*)alloc((size_t)BB * HH * 4);
  p.feed  = (float*)alloc((size_t)BB * HH * 4);
  p.part1 = (float*)alloc((size_t)BB * GG * 4);
  p.ctx   = (float*)alloc((size_t)BB * HH * 4);
  p.scg   = (float*)alloc((size_t)BB * SS * 4);
  p.flag  = (unsigned int*)alloc(128 * 4);

  hipLaunchKernelGGL(prep_weights, dim3(4096), dim3(256), 0, stream, p);
  hipLaunchKernelGGL(prep_mw, dim3(4096), dim3(256), 0, stream, p);
  hipLaunchKernelGGL(prep_eg, dim3(8192), dim3(256), 0, stream, p);
  void* args[] = {(void*)&p};
  hipLaunchCooperativeKernel((void*)decoder_main, dim3(256), dim3(256), args, 0, stream);
}

// Round 10
// 4674.532 us; speedup vs baseline: 2.7967x; 1.0657x over previous
//
#include <hip/hip_runtime.h>
#include <hip/hip_bf16.h>

typedef __bf16 bf16x8 __attribute__((ext_vector_type(8)));
typedef unsigned short u16x8 __attribute__((ext_vector_type(8)));
typedef float f32x4 __attribute__((ext_vector_type(4)));

constexpr int TT = 64;   // timesteps
constexpr int BB = 64;   // batch
constexpr int SS = 128;  // memory length
constexpr int HH = 512;  // hidden
constexpr int GG = 2048; // 4*H

// weight sizes (elements); hi at [0], lo at [N]
constexpr int NW0E = 2048 * 512;
constexpr int NW0R = 2048 * 1024;
constexpr int NW1  = 2048 * 512;
constexpr int NWO  = 512 * 1024;
constexpr int NWI  = 512 * 512;

struct P {
  const int* tok; const float* mbank; const int* len;
  const float* h0_in; const float* c0_in; const float* emb;
  const float* w_ih0; const float* w_hh0; const float* b_ih0; const float* b_hh0;
  const float* w_ih1; const float* w_hh1; const float* b_ih1; const float* b_hh1;
  const float* w_in; const float* w_out;
  float* out_dec; float* out_attn; float* out_hf; float* out_cf;
  unsigned short *W0E, *W0R, *Wih1, *Whh1, *Wout, *WinT;
  float *EGb;                             // f32: score-path precision
  float *Mw;
  float *b0, *b1, *h0buf, *h1s, *c0s, *c1s, *feed, *part1, *ctx, *scg;
  unsigned int* flag;  // [0..63] score flags, [256..511] per-WG barrier epochs
};

__device__ __forceinline__ unsigned short f2bf(float f) {
  unsigned int u = __builtin_bit_cast(unsigned int, f);
  return (unsigned short)((u + 0x7fffu + ((u >> 16) & 1u)) >> 16);
}
__device__ __forceinline__ float bf2f(unsigned short h) {
  return __builtin_bit_cast(float, ((unsigned int)h) << 16);
}
__device__ __forceinline__ bf16x8 ldb(const unsigned short* p) {
  return __builtin_bit_cast(bf16x8, *(const u16x8*)p);
}
__device__ __forceinline__ f32x4 mfma_(bf16x8 a, bf16x8 b, f32x4 c) {
  return __builtin_amdgcn_mfma_f32_16x16x32_bf16(a, b, c, 0, 0, 0);
}
__device__ __forceinline__ float sigm(float x) { return 1.f / (1.f + __expf(-x)); }
__device__ __forceinline__ f32x4 zero4() { f32x4 z = {0.f, 0.f, 0.f, 0.f}; return z; }

#define ATL(pp) __hip_atomic_load((pp), __ATOMIC_RELAXED, __HIP_MEMORY_SCOPE_AGENT)
#define ATS(pp, vv) __hip_atomic_store((pp), (vv), __ATOMIC_RELAXED, __HIP_MEMORY_SCOPE_AGENT)
#define ATA(pp, vv) __hip_atomic_fetch_add((pp), (vv), __ATOMIC_RELAXED, __HIP_MEMORY_SCOPE_AGENT)

__device__ __forceinline__ void splitA(const float* s, bf16x8& hi, bf16x8& lo) {
  float4 a0 = *(const float4*)s;
  float4 a1 = *(const float4*)(s + 4);
  float v[8] = {a0.x, a0.y, a0.z, a0.w, a1.x, a1.y, a1.z, a1.w};
  u16x8 h, l;
#pragma unroll
  for (int j = 0; j < 8; ++j) {
    unsigned short hb = f2bf(v[j]);
    h[j] = hb;
    l[j] = f2bf(v[j] - bf2f(hb));
  }
  hi = __builtin_bit_cast(bf16x8, h);
  lo = __builtin_bit_cast(bf16x8, l);
}
__device__ __forceinline__ f32x4 mfma3(bf16x8 ah, bf16x8 al, bf16x8 bh, bf16x8 bl, f32x4 c) {
  c = mfma_(al, bh, c);
  c = mfma_(ah, bl, c);
  c = mfma_(ah, bh, c);
  return c;
}

// ---------------- prep: weight split / transpose / state init ----------------
__global__ void prep_weights(P p) {
  constexpr int TOT = NW0E + NW0R + NW1 + NW1 + NWO + NWI + 2048 + 2048 +
                      32768 * 5 + 8192 + 1024;
  for (int i = blockIdx.x * blockDim.x + threadIdx.x; i < TOT;
       i += gridDim.x * blockDim.x) {
    int j = i;
    float v; unsigned short* dst; int N;
    if (j < NW0E) {              // emb part of w_ih0: [2048][512]
      int n = j >> 9, k = j & 511;
      v = p.w_ih0[n * 1024 + k];
      dst = p.W0E; N = NW0E; goto split;
    }
    j -= NW0E;
    if (j < NW0R) {              // [feed | h] : [2048][1024]
      int n = j >> 10, k = j & 1023;
      v = (k < 512) ? p.w_ih0[n * 1024 + 512 + k] : p.w_hh0[n * 512 + (k - 512)];
      dst = p.W0R; N = NW0R; goto split;
    }
    j -= NW0R;
    if (j < NW1) { v = p.w_ih1[j]; dst = p.Wih1; N = NW1; goto split; }
    j -= NW1;
    if (j < NW1) { v = p.w_hh1[j]; dst = p.Whh1; N = NW1; goto split; }
    j -= NW1;
    if (j < NWO) { v = p.w_out[j]; dst = p.Wout; N = NWO; goto split; }
    j -= NWO;
    if (j < NWI) {               // WinT[n][k] = w_in[k][n]
      int n = j >> 9, q = j & 511;
      v = p.w_in[q * 512 + n];
      dst = p.WinT; N = NWI; goto split;
    }
    j -= NWI;
    if (j < 2048) { p.b0[j] = p.b_ih0[j] + p.b_hh0[j]; continue; }
    j -= 2048;
    if (j < 2048) { p.b1[j] = p.b_ih1[j] + p.b_hh1[j]; continue; }
    j -= 2048;
    if (j < 32768) { p.h0buf[j] = p.h0_in[j]; continue; }
    j -= 32768;
    if (j < 32768) { p.h1s[j] = p.h0_in[32768 + j]; continue; }
    j -= 32768;
    if (j < 32768) { p.c0s[j] = p.c0_in[j]; continue; }
    j -= 32768;
    if (j < 32768) { p.c1s[j] = p.c0_in[32768 + j]; continue; }
    j -= 32768;
    if (j < 32768) { p.feed[j] = 0.f; continue; }
    j -= 32768;
    if (j < 8192) { p.scg[j] = 0.f; continue; }
    j -= 8192;
    p.flag[j] = 0u;
    continue;
  split:
    {
      unsigned short hb = f2bf(v);
      dst[j] = hb;
      dst[N + j] = f2bf(v - bf2f(hb));
    }
  }
}

// ---------------- prep: Mw[b,s,n] = sum_k M[b,s,k] * w_in[k,n]  (f32) ----------------
__global__ void prep_mw(P p) {
  const int wg = blockIdx.x;             // 4096 = 128 m-blocks x 32 n-tiles
  const int bm = wg & 127, bn = wg >> 7;
  const int tid = threadIdx.x, wave = tid >> 6, lane = tid & 63;
  const int arow = lane & 15, kq = (lane >> 4) * 8;
  const int m0 = bm * 64 + wave * 16;
  const int n0 = bn * 16;
  const float* A = p.mbank + (size_t)(m0 + arow) * HH;
  const unsigned short* Bp = p.WinT + (size_t)(n0 + arow) * HH + kq;
  f32x4 acc = zero4();
  for (int kk = 0; kk < HH; kk += 32) {
    bf16x8 ah, al;
    splitA(A + kk + kq, ah, al);
    acc = mfma3(ah, al, ldb(Bp + kk), ldb(Bp + NWI + kk), acc);
  }
  const int r0 = m0 + (lane >> 4) * 4;
#pragma unroll
  for (int r = 0; r < 4; ++r)
    p.Mw[(size_t)(r0 + r) * HH + n0 + arow] = acc[r];
}

// ---------------- prep: EGb[t*64+b, n] = emb[tok] @ W0E^T + b0  (f32) ----------------
__global__ void prep_eg(P p) {
  const int wg = blockIdx.x;             // 8192 = 64 m-blocks x 128 n-tiles
  const int bn = wg & 127, bm = wg >> 7;
  const int tid = threadIdx.x, wave = tid >> 6, lane = tid & 63;
  const int arow = lane & 15, kq = (lane >> 4) * 8;
  const int m0 = bm * 64 + wave * 16;    // flat row in [0,4096)
  const int n0 = bn * 16;
  const int token = p.tok[m0 + arow];
  const float* A = p.emb + (size_t)token * 512;
  const unsigned short* Bp = p.W0E + (size_t)(n0 + arow) * 512 + kq;
  f32x4 acc = zero4();
  for (int kk = 0; kk < 512; kk += 32) {
    bf16x8 ah, al;
    splitA(A + kk + kq, ah, al);
    acc = mfma3(ah, al, ldb(Bp + kk), ldb(Bp + NW0E + kk), acc);
  }
  const int r0 = m0 + (lane >> 4) * 4;
  const float bb = p.b0[n0 + arow];
#pragma unroll
  for (int r = 0; r < 4; ++r)
    p.EGb[(size_t)(r0 + r) * 2048 + n0 + arow] = acc[r] + bb;
}

// ---------------- persistent decoder: 256 WGs x 256 threads ----------------
__global__ void __launch_bounds__(256) decoder_main(P p) {
  const int wg = blockIdx.x, tid = threadIdx.x;
  const int wave = tid >> 6, lane = tid & 63;
  const int arow = lane & 15;            // fragment row (A: m, B: n)
  const int kq = (lane >> 4) * 8;
  unsigned nb = 0;                       // barrier epoch

  __shared__ float MwL[32][512];          // 64 KB: pinned Mw quarter (f32)
  __shared__ float Aslab[16][516];        // 33 KB: staged GEMM A operand
  __shared__ float exch[4][16][16];       // gate exchange
  __shared__ float scl[128];
  __shared__ float pl[128];

  const int attb = wg >> 2, attq = wg & 3;
  for (int idx = tid; idx < 32 * 512; idx += 256) {
    int r = idx >> 9, c = idx & 511;
    MwL[r][c] = p.Mw[(size_t)(attb * 128 + attq * 32 + r) * 512 + c];
  }

  const int w2 = (wg < 128) ? wg : wg - 128;
  const int strip = w2 & 31;
  const int mblk = w2 >> 5;
  const int gate = wave;
  const int colj = strip * 16 + arow;

  // contention-free grid barrier: per-WG epoch slot + wave-parallel poll
  auto gbar = [&]() {
    ++nb;
    asm volatile("s_waitcnt vmcnt(0)" ::: "memory");   // drain this wave's stores
    __syncthreads();
    if (tid == 0) ATS(&p.flag[256 + wg], nb);          // own slot: no RMW contention
    for (;;) {
      unsigned v = ATL(&p.flag[256 + tid]);            // 256 parallel LLC loads
      if (__syncthreads_count((int)(v < nb)) == 0) break;
      __builtin_amdgcn_s_sleep(1);
    }
  };

  auto stageC = [&](const float* base) { // [16][512] row-major -> Aslab (LLC-coherent)
    __syncthreads();
    float4 v[8];
    const float* ap[8];
#pragma unroll
    for (int j = 0; j < 8; ++j) {
      int idx = tid * 4 + j * 1024;
      ap[j] = base + (idx >> 9) * 512 + (idx & 511);
    }
#pragma unroll
    for (int j = 0; j < 8; ++j)
      asm volatile("global_load_dwordx4 %0, %1, off sc0 sc1" : "=v"(v[j]) : "v"(ap[j]));
    asm volatile("s_waitcnt vmcnt(0)" ::: "memory");
    __builtin_amdgcn_sched_barrier(0);
#pragma unroll
    for (int j = 0; j < 8; ++j) {
      int idx = tid * 4 + j * 1024;
      *(float4*)&Aslab[idx >> 9][idx & 511] = v[j];
    }
    __syncthreads();
  };
  auto gemm_half = [&](const unsigned short* whi, const unsigned short* wlo,
                       f32x4 acc) {
#pragma unroll 4
    for (int kk = 0; kk < 512; kk += 32) {
      bf16x8 ah, al;
      splitA(&Aslab[arow][kk + kq], ah, al);
      acc = mfma3(ah, al, ldb(whi + kk), ldb(wlo + kk), acc);
    }
    return acc;
  };

  for (int t = 0; t < TT; ++t) {
    const float* h0c = p.h0buf + (t & 1) * (BB * HH);
    float* h0n = p.h0buf + ((t + 1) & 1) * (BB * HH);

    // ---- P1: gates0+cell0 (wg<128) || h1_prev @ Whh1 + b1 (wg>=128) ----
    if (wg < 128) {
      const size_t wr = (size_t)(gate * 512 + colj) * 1024;
      f32x4 acc = zero4();
      stageC(p.feed + mblk * 16 * 512);
      acc = gemm_half(p.W0R + wr + kq, p.W0R + NW0R + wr + kq, acc);
      stageC(h0c + mblk * 16 * 512);
      acc = gemm_half(p.W0R + wr + 512 + kq, p.W0R + NW0R + wr + 512 + kq, acc);
      const float* eg =
          p.EGb + ((size_t)(t * 64 + mblk * 16)) * 2048 + gate * 512 + colj;
#pragma unroll
      for (int r = 0; r < 4; ++r) {
        acc[r] += eg[((lane >> 4) * 4 + r) * 2048];
        exch[gate][(lane >> 4) * 4 + r][arow] = acc[r];
      }
      __syncthreads();
      {
        int br = tid >> 4, nc = tid & 15;
        int idx = (mblk * 16 + br) * 512 + strip * 16 + nc;
        float iv = sigm(exch[0][br][nc]);
        float fv = sigm(exch[1][br][nc]);
        float gv = tanhf(exch[2][br][nc]);
        float ov = sigm(exch[3][br][nc]);
        float cn = fv * p.c0s[idx] + iv * gv;
        p.c0s[idx] = cn;
        float hv = ov * tanhf(cn);
        ATS(&h0n[idx], hv);
        if (t == TT - 1) { p.out_cf[idx] = cn; p.out_hf[idx] = hv; }
      }
    } else {
      const size_t wr = (size_t)(gate * 512 + colj) * 512;
      stageC(p.h1s + mblk * 16 * 512);
      f32x4 acc = gemm_half(p.Whh1 + wr + kq, p.Whh1 + NW1 + wr + kq, zero4());
      const float bb = p.b1[gate * 512 + colj];
#pragma unroll
      for (int r = 0; r < 4; ++r)
        ATS(&p.part1[(mblk * 16 + (lane >> 4) * 4 + r) * 2048 + gate * 512 + colj],
            acc[r] + bb);
    }
    gbar();

    // ---- P2: gates1(ih part) + part1 + cell1 (wg<128); ctx zero (128..159) ----
    if (wg < 128) {
      const size_t wr = (size_t)(gate * 512 + colj) * 512;
      stageC(h0n + mblk * 16 * 512);
      f32x4 acc = gemm_half(p.Wih1 + wr + kq, p.Wih1 + NW1 + wr + kq, zero4());
#pragma unroll
      for (int r = 0; r < 4; ++r) {
        acc[r] += ATL(&p.part1[(mblk * 16 + (lane >> 4) * 4 + r) * 2048 +
                               gate * 512 + colj]);
        exch[gate][(lane >> 4) * 4 + r][arow] = acc[r];
      }
      __syncthreads();
      {
        int br = tid >> 4, nc = tid & 15;
        int idx = (mblk * 16 + br) * 512 + strip * 16 + nc;
        float iv = sigm(exch[0][br][nc]);
        float fv = sigm(exch[1][br][nc]);
        float gv = tanhf(exch[2][br][nc]);
        float ov = sigm(exch[3][br][nc]);
        float cn = fv * p.c1s[idx] + iv * gv;
        p.c1s[idx] = cn;
        float hv = ov * tanhf(cn);
        ATS(&p.h1s[idx], hv);
        if (t == TT - 1) { p.out_cf[BB * HH + idx] = cn; p.out_hf[BB * HH + idx] = hv; }
      }
    } else if (wg < 160) {
      int base = (wg - 128) * 1024 + tid * 4;
#pragma unroll
      for (int i = 0; i < 4; ++i) ATS(&p.ctx[base + i], 0.f);
    }
    gbar();

    // ---- P3: attention (4 WGs per batch; scores from LDS Mw, ctx from f32 mbank) ----
    {
      float h8[8];
      {
        const float* hp = p.h1s + attb * 512 + lane * 8;
        float4 a, c;
        asm volatile("global_load_dwordx4 %0, %1, off sc0 sc1" : "=v"(a) : "v"(hp));
        asm volatile("global_load_dwordx4 %0, %1, off sc0 sc1" : "=v"(c) : "v"(hp + 4));
        asm volatile("s_waitcnt vmcnt(0)" ::: "memory");
        __builtin_amdgcn_sched_barrier(0);
        h8[0] = a.x; h8[1] = a.y; h8[2] = a.z; h8[3] = a.w;
        h8[4] = c.x; h8[5] = c.y; h8[6] = c.z; h8[7] = c.w;
      }
#pragma unroll
      for (int i = 0; i < 8; ++i) {
        const int sl = wave * 8 + i;
        const float* mw = &MwL[sl][lane * 8];
        float d = h8[0] * mw[0] + h8[1] * mw[1] + h8[2] * mw[2] + h8[3] * mw[3] +
                  h8[4] * mw[4] + h8[5] * mw[5] + h8[6] * mw[6] + h8[7] * mw[7];
#pragma unroll
        for (int o = 32; o; o >>= 1) d += __shfl_xor(d, o);
        if (lane == 0) ATS(&p.scg[attb * 128 + attq * 32 + sl], d);
      }
      asm volatile("s_waitcnt vmcnt(0)" ::: "memory");
      __syncthreads();                   // all score stores drained
      if (tid == 0) {
        ATA(&p.flag[attb], 1u);
        const unsigned tgt = 4u * (unsigned)(t + 1);
        while (ATL(&p.flag[attb]) < tgt) __builtin_amdgcn_s_sleep(1);
      }
      __syncthreads();
      if (tid < 128) scl[tid] = ATL(&p.scg[attb * 128 + tid]);
      __syncthreads();
      if (wave == 0) {
        const int lenb = p.len[attb];
        float s0 = (lane < lenb) ? scl[lane] : -__builtin_inff();
        float s1 = (lane + 64 < lenb) ? scl[lane + 64] : -__builtin_inff();
        float mx = fmaxf(s0, s1);
#pragma unroll
        for (int o = 32; o; o >>= 1) mx = fmaxf(mx, __shfl_xor(mx, o));
        float e0 = (lane < lenb) ? __expf(s0 - mx) : 0.f;
        float e1 = (lane + 64 < lenb) ? __expf(s1 - mx) : 0.f;
        float sm = e0 + e1;
#pragma unroll
        for (int o = 32; o; o >>= 1) sm += __shfl_xor(sm, o);
        float inv = 1.f / sm;
        pl[lane] = e0 * inv; pl[lane + 64] = e1 * inv;
        if (attq == 0) {
          float* ao = p.out_attn + ((size_t)t * BB + attb) * SS;
          ao[lane] = e0 * inv; ao[lane + 64] = e1 * inv;
        }
      }
      __syncthreads();
      {
        const float* MbB = p.mbank + (size_t)(attb * 128 + attq * 32) * 512;
        const int h2 = tid * 2;
        float ca = 0.f, cb = 0.f;
#pragma unroll 4
        for (int s = 0; s < 32; ++s) {
          float ps = pl[attq * 32 + s];
          float2 v = *(const float2*)(MbB + (size_t)s * 512 + h2);
          ca += ps * v.x;
          cb += ps * v.y;
        }
        atomicAdd(&p.ctx[attb * 512 + h2], ca);
        atomicAdd(&p.ctx[attb * 512 + h2 + 1], cb);
      }
    }
    gbar();

    // ---- P4: attn_h = tanh([ctx | h1] @ Wout^T) -> out_dec, feed ----
    if (wg < 32) {
      const int m4 = wg >> 3, ngrp = wg & 7;
      const int nstrip = ngrp * 4 + wave;
      const int cj = nstrip * 16 + arow;
      const size_t wr = (size_t)cj * 1024;
      f32x4 acc = zero4();
      stageC(p.ctx + m4 * 16 * 512);
      acc = gemm_half(p.Wout + wr + kq, p.Wout + NWO + wr + kq, acc);
      stageC(p.h1s + m4 * 16 * 512);
      acc = gemm_half(p.Wout + wr + 512 + kq, p.Wout + NWO + wr + 512 + kq, acc);
      float* dec = p.out_dec + (size_t)t * BB * HH;
#pragma unroll
      for (int r = 0; r < 4; ++r) {
        int b = m4 * 16 + (lane >> 4) * 4 + r;
        float v = tanhf(acc[r]);
        dec[b * 512 + cj] = v;
        ATS(&p.feed[b * 512 + cj], v);
      }
    }
    gbar();
  }
}

extern "C" void kernel_launch(void* const* d_in, const int* in_sizes, int n_in,
                              void* d_out, int out_size, void* d_ws, size_t ws_size,
                              hipStream_t stream) {
  P p;
  p.tok   = (const int*)d_in[0];
  p.mbank = (const float*)d_in[1];
  p.len   = (const int*)d_in[2];
  p.h0_in = (const float*)d_in[3];
  p.c0_in = (const float*)d_in[4];
  p.emb   = (const float*)d_in[5];
  p.w_ih0 = (const float*)d_in[6];
  p.w_hh0 = (const float*)d_in[7];
  p.b_ih0 = (const float*)d_in[8];
  p.b_hh0 = (const float*)d_in[9];
  p.w_ih1 = (const float*)d_in[10];
  p.w_hh1 = (const float*)d_in[11];
  p.b_ih1 = (const float*)d_in[12];
  p.b_hh1 = (const float*)d_in[13];
  p.w_in  = (const float*)d_in[14];
  p.w_out = (const float*)d_in[15];

  float* out = (float*)d_out;
  p.out_dec  = out;
  p.out_attn = out + (size_t)TT * BB * HH;
  p.out_hf   = out + (size_t)TT * BB * HH + (size_t)TT * BB * SS;
  p.out_cf   = p.out_hf + 2 * BB * HH;

  char* w = (char*)d_ws;
  auto alloc = [&](size_t n) { char* r = w; w += (n + 255) & ~(size_t)255; return r; };
  p.W0E   = (unsigned short*)alloc((size_t)NW0E * 2 * 2);
  p.W0R   = (unsigned short*)alloc((size_t)NW0R * 2 * 2);
  p.Wih1  = (unsigned short*)alloc((size_t)NW1 * 2 * 2);
  p.Whh1  = (unsigned short*)alloc((size_t)NW1 * 2 * 2);
  p.Wout  = (unsigned short*)alloc((size_t)NWO * 2 * 2);
  p.WinT  = (unsigned short*)alloc((size_t)NWI * 2 * 2);
  p.EGb   = (float*)alloc((size_t)4096 * 2048 * 4);
  p.Mw    = (float*)alloc((size_t)BB * SS * HH * 4);
  p.b0    = (float*)alloc(2048 * 4);
  p.b1    = (float*)alloc(2048 * 4);
  p.h0buf = (float*)alloc((size_t)2 * BB * HH * 4);
  p.h1s   = (float*)alloc((size_t)BB * HH * 4);
  p.c0s   = (float*)alloc((size_t)BB * HH * 4);
  p.c1s   = (float*)alloc((size_t)BB * HH * 4);
  p.feed  = (float*)alloc((size_t)BB * HH * 4);
  p.part1 = (float*)alloc((size_t)BB * GG * 4);
  p.ctx   = (float*)alloc((size_t)BB * HH * 4);
  p.scg   = (float*)alloc((size_t)BB * SS * 4);
  p.flag  = (unsigned int*)alloc(1024 * 4);

  hipLaunchKernelGGL(prep_weights, dim3(4096), dim3(256), 0, stream, p);
  hipLaunchKernelGGL(prep_mw, dim3(4096), dim3(256), 0, stream, p);
  hipLaunchKernelGGL(prep_eg, dim3(8192), dim3(256), 0, stream, p);
  void* args[] = {(void*)&p};
  hipLaunchCooperativeKernel((void*)decoder_main, dim3(256), dim3(256), args, 0, stream);
}

// Round 11
// 3895.130 us; speedup vs baseline: 3.3563x; 1.2001x over previous
//
#include <hip/hip_runtime.h>
#include <hip/hip_bf16.h>

typedef __bf16 bf16x8 __attribute__((ext_vector_type(8)));
typedef unsigned short u16x8 __attribute__((ext_vector_type(8)));
typedef float f32x4 __attribute__((ext_vector_type(4)));

constexpr int TT = 64;   // timesteps
constexpr int BB = 64;   // batch
constexpr int SS = 128;  // memory length
constexpr int HH = 512;  // hidden
constexpr int GG = 2048; // 4*H

// weight sizes (elements); hi at [0], lo at [N]
constexpr int NW0E = 2048 * 512;
constexpr int NW0R = 2048 * 1024;
constexpr int NW1  = 2048 * 512;
constexpr int NWO  = 512 * 1024;
constexpr int NWI  = 512 * 512;

struct P {
  const int* tok; const float* mbank; const int* len;
  const float* h0_in; const float* c0_in; const float* emb;
  const float* w_ih0; const float* w_hh0; const float* b_ih0; const float* b_hh0;
  const float* w_ih1; const float* w_hh1; const float* b_ih1; const float* b_hh1;
  const float* w_in; const float* w_out;
  float* out_dec; float* out_attn; float* out_hf; float* out_cf;
  unsigned short *W0E, *W0R, *Wih1, *Whh1, *Wout, *WinT;
  float *EGb;                             // f32: score-path precision
  float *Mw;
  float *b0, *b1, *h0buf, *h1s, *c0s, *c1s, *feed, *part1, *ctx, *scg;
  unsigned int* flag;  // [0..63] score flags, [128 + g*128 + u] group barrier slots
};

__device__ __forceinline__ unsigned short f2bf(float f) {
  unsigned int u = __builtin_bit_cast(unsigned int, f);
  return (unsigned short)((u + 0x7fffu + ((u >> 16) & 1u)) >> 16);
}
__device__ __forceinline__ float bf2f(unsigned short h) {
  return __builtin_bit_cast(float, ((unsigned int)h) << 16);
}
__device__ __forceinline__ bf16x8 ldb(const unsigned short* p) {
  return __builtin_bit_cast(bf16x8, *(const u16x8*)p);
}
__device__ __forceinline__ f32x4 mfma_(bf16x8 a, bf16x8 b, f32x4 c) {
  return __builtin_amdgcn_mfma_f32_16x16x32_bf16(a, b, c, 0, 0, 0);
}
__device__ __forceinline__ float sigm(float x) { return 1.f / (1.f + __expf(-x)); }
__device__ __forceinline__ f32x4 zero4() { f32x4 z = {0.f, 0.f, 0.f, 0.f}; return z; }

#define ATL(pp) __hip_atomic_load((pp), __ATOMIC_RELAXED, __HIP_MEMORY_SCOPE_AGENT)
#define ATS(pp, vv) __hip_atomic_store((pp), (vv), __ATOMIC_RELAXED, __HIP_MEMORY_SCOPE_AGENT)
#define ATA(pp, vv) __hip_atomic_fetch_add((pp), (vv), __ATOMIC_RELAXED, __HIP_MEMORY_SCOPE_AGENT)

__device__ __forceinline__ void splitA(const float* s, bf16x8& hi, bf16x8& lo) {
  float4 a0 = *(const float4*)s;
  float4 a1 = *(const float4*)(s + 4);
  float v[8] = {a0.x, a0.y, a0.z, a0.w, a1.x, a1.y, a1.z, a1.w};
  u16x8 h, l;
#pragma unroll
  for (int j = 0; j < 8; ++j) {
    unsigned short hb = f2bf(v[j]);
    h[j] = hb;
    l[j] = f2bf(v[j] - bf2f(hb));
  }
  hi = __builtin_bit_cast(bf16x8, h);
  lo = __builtin_bit_cast(bf16x8, l);
}
__device__ __forceinline__ f32x4 mfma3(bf16x8 ah, bf16x8 al, bf16x8 bh, bf16x8 bl, f32x4 c) {
  c = mfma_(al, bh, c);
  c = mfma_(ah, bl, c);
  c = mfma_(ah, bh, c);
  return c;
}

// ---------------- prep: weight split / transpose / state init ----------------
__global__ void prep_weights(P p) {
  constexpr int TOT = NW0E + NW0R + NW1 + NW1 + NWO + NWI + 2048 + 2048 +
                      32768 * 5 + 8192 + 1024;
  for (int i = blockIdx.x * blockDim.x + threadIdx.x; i < TOT;
       i += gridDim.x * blockDim.x) {
    int j = i;
    float v; unsigned short* dst; int N;
    if (j < NW0E) {              // emb part of w_ih0: [2048][512]
      int n = j >> 9, k = j & 511;
      v = p.w_ih0[n * 1024 + k];
      dst = p.W0E; N = NW0E; goto split;
    }
    j -= NW0E;
    if (j < NW0R) {              // [feed | h] : [2048][1024]
      int n = j >> 10, k = j & 1023;
      v = (k < 512) ? p.w_ih0[n * 1024 + 512 + k] : p.w_hh0[n * 512 + (k - 512)];
      dst = p.W0R; N = NW0R; goto split;
    }
    j -= NW0R;
    if (j < NW1) { v = p.w_ih1[j]; dst = p.Wih1; N = NW1; goto split; }
    j -= NW1;
    if (j < NW1) { v = p.w_hh1[j]; dst = p.Whh1; N = NW1; goto split; }
    j -= NW1;
    if (j < NWO) { v = p.w_out[j]; dst = p.Wout; N = NWO; goto split; }
    j -= NWO;
    if (j < NWI) {               // WinT[n][k] = w_in[k][n]
      int n = j >> 9, q = j & 511;
      v = p.w_in[q * 512 + n];
      dst = p.WinT; N = NWI; goto split;
    }
    j -= NWI;
    if (j < 2048) { p.b0[j] = p.b_ih0[j] + p.b_hh0[j]; continue; }
    j -= 2048;
    if (j < 2048) { p.b1[j] = p.b_ih1[j] + p.b_hh1[j]; continue; }
    j -= 2048;
    if (j < 32768) { p.h0buf[j] = p.h0_in[j]; continue; }
    j -= 32768;
    if (j < 32768) { p.h1s[j] = p.h0_in[32768 + j]; continue; }
    j -= 32768;
    if (j < 32768) { p.c0s[j] = p.c0_in[j]; continue; }
    j -= 32768;
    if (j < 32768) { p.c1s[j] = p.c0_in[32768 + j]; continue; }
    j -= 32768;
    if (j < 32768) { p.feed[j] = 0.f; continue; }
    j -= 32768;
    if (j < 8192) { p.scg[j] = 0.f; continue; }
    j -= 8192;
    p.flag[j] = 0u;
    continue;
  split:
    {
      unsigned short hb = f2bf(v);
      dst[j] = hb;
      dst[N + j] = f2bf(v - bf2f(hb));
    }
  }
}

// ---------------- prep: Mw[b,s,n] = sum_k M[b,s,k] * w_in[k,n]  (f32) ----------------
__global__ void prep_mw(P p) {
  const int wg = blockIdx.x;             // 4096 = 128 m-blocks x 32 n-tiles
  const int bm = wg & 127, bn = wg >> 7;
  const int tid = threadIdx.x, wave = tid >> 6, lane = tid & 63;
  const int arow = lane & 15, kq = (lane >> 4) * 8;
  const int m0 = bm * 64 + wave * 16;
  const int n0 = bn * 16;
  const float* A = p.mbank + (size_t)(m0 + arow) * HH;
  const unsigned short* Bp = p.WinT + (size_t)(n0 + arow) * HH + kq;
  f32x4 acc = zero4();
  for (int kk = 0; kk < HH; kk += 32) {
    bf16x8 ah, al;
    splitA(A + kk + kq, ah, al);
    acc = mfma3(ah, al, ldb(Bp + kk), ldb(Bp + NWI + kk), acc);
  }
  const int r0 = m0 + (lane >> 4) * 4;
#pragma unroll
  for (int r = 0; r < 4; ++r)
    p.Mw[(size_t)(r0 + r) * HH + n0 + arow] = acc[r];
}

// ---------------- prep: EGb[t*64+b, n] = emb[tok] @ W0E^T + b0  (f32) ----------------
__global__ void prep_eg(P p) {
  const int wg = blockIdx.x;             // 8192 = 64 m-blocks x 128 n-tiles
  const int bn = wg & 127, bm = wg >> 7;
  const int tid = threadIdx.x, wave = tid >> 6, lane = tid & 63;
  const int arow = lane & 15, kq = (lane >> 4) * 8;
  const int m0 = bm * 64 + wave * 16;    // flat row in [0,4096)
  const int n0 = bn * 16;
  const int token = p.tok[m0 + arow];
  const float* A = p.emb + (size_t)token * 512;
  const unsigned short* Bp = p.W0E + (size_t)(n0 + arow) * 512 + kq;
  f32x4 acc = zero4();
  for (int kk = 0; kk < 512; kk += 32) {
    bf16x8 ah, al;
    splitA(A + kk + kq, ah, al);
    acc = mfma3(ah, al, ldb(Bp + kk), ldb(Bp + NW0E + kk), acc);
  }
  const int r0 = m0 + (lane >> 4) * 4;
  const float bb = p.b0[n0 + arow];
#pragma unroll
  for (int r = 0; r < 4; ++r)
    p.EGb[(size_t)(r0 + r) * 2048 + n0 + arow] = acc[r] + bb;
}

// ---------------- persistent decoder: 4 independent groups x 64 WGs ----------------
__global__ void __launch_bounds__(256) decoder_main(P p) {
  const int wg = blockIdx.x, tid = threadIdx.x;
  const int wave = tid >> 6, lane = tid & 63;
  const int arow = lane & 15;            // fragment row (A: m, B: n)
  const int kq = (lane >> 4) * 8;
  const int g = wg >> 6;                 // group 0..3 (owns batches 16g..16g+16)
  const int u = wg & 63;                 // WG index within group
  unsigned nb = 0;                       // group-barrier epoch

  __shared__ float MwL[32][512];          // 64 KB: pinned Mw quarter (f32)
  __shared__ float Aslab[16][516];        // 33 KB: staged GEMM A operand
  __shared__ float exch[4][16][16];       // gate exchange
  __shared__ float scl[128];
  __shared__ float pl[128];

  const int attb = (g << 4) + (u >> 2);  // this WG's attention batch
  const int attq = u & 3;                // quarter within batch
  for (int idx = tid; idx < 32 * 512; idx += 256) {
    int r = idx >> 9, c = idx & 511;
    MwL[r][c] = p.Mw[(size_t)(attb * 128 + attq * 32 + r) * 512 + c];
  }

  const int w2 = (u < 32) ? u : u - 32;
  const int strip = w2;                  // 16-col strip (32 strips = 512 cols)
  const int gate = wave;
  const int colj = strip * 16 + arow;
  const int rowbase = g * 16 * 512;      // group's 16 batch rows

  // group barrier: 64 per-WG epoch slots, one-wave parallel poll
  unsigned* slots = p.flag + 128 + g * 128;
  auto gbar = [&]() {
    ++nb;
    asm volatile("s_waitcnt vmcnt(0)" ::: "memory");
    __syncthreads();
    if (tid == 0) ATS(&slots[u], nb);
    for (;;) {
      unsigned v = (tid < 64) ? ATL(&slots[tid]) : nb;
      if (__syncthreads_count((int)(v < nb)) == 0) break;
    }
  };

  auto stageC = [&](const float* base) { // [16][512] row-major -> Aslab (LLC-coherent)
    __syncthreads();
    float4 v[8];
    const float* ap[8];
#pragma unroll
    for (int j = 0; j < 8; ++j) {
      int idx = tid * 4 + j * 1024;
      ap[j] = base + (idx >> 9) * 512 + (idx & 511);
    }
#pragma unroll
    for (int j = 0; j < 8; ++j)
      asm volatile("global_load_dwordx4 %0, %1, off sc0 sc1" : "=v"(v[j]) : "v"(ap[j]));
    asm volatile("s_waitcnt vmcnt(0)" ::: "memory");
    __builtin_amdgcn_sched_barrier(0);
#pragma unroll
    for (int j = 0; j < 8; ++j) {
      int idx = tid * 4 + j * 1024;
      *(float4*)&Aslab[idx >> 9][idx & 511] = v[j];
    }
    __syncthreads();
  };
  auto gemm_half = [&](const unsigned short* whi, const unsigned short* wlo,
                       f32x4 acc) {
#pragma unroll 4
    for (int kk = 0; kk < 512; kk += 32) {
      bf16x8 ah, al;
      splitA(&Aslab[arow][kk + kq], ah, al);
      acc = mfma3(ah, al, ldb(whi + kk), ldb(wlo + kk), acc);
    }
    return acc;
  };

  for (int t = 0; t < TT; ++t) {
    const float* h0c = p.h0buf + (t & 1) * (BB * HH);
    float* h0n = p.h0buf + ((t + 1) & 1) * (BB * HH);

    // ---- P1: gates0+cell0 (u<32) || h1_prev @ Whh1 + b1 (u>=32) ----
    if (u < 32) {
      const size_t wr = (size_t)(gate * 512 + colj) * 1024;
      f32x4 acc = zero4();
      stageC(p.feed + rowbase);
      acc = gemm_half(p.W0R + wr + kq, p.W0R + NW0R + wr + kq, acc);
      stageC(h0c + rowbase);
      acc = gemm_half(p.W0R + wr + 512 + kq, p.W0R + NW0R + wr + 512 + kq, acc);
      const float* eg =
          p.EGb + ((size_t)(t * 64 + g * 16)) * 2048 + gate * 512 + colj;
#pragma unroll
      for (int r = 0; r < 4; ++r) {
        acc[r] += eg[((lane >> 4) * 4 + r) * 2048];
        exch[gate][(lane >> 4) * 4 + r][arow] = acc[r];
      }
      __syncthreads();
      {
        int br = tid >> 4, nc = tid & 15;
        int idx = rowbase + br * 512 + strip * 16 + nc;
        float iv = sigm(exch[0][br][nc]);
        float fv = sigm(exch[1][br][nc]);
        float gv = tanhf(exch[2][br][nc]);
        float ov = sigm(exch[3][br][nc]);
        float cn = fv * p.c0s[idx] + iv * gv;
        p.c0s[idx] = cn;
        float hv = ov * tanhf(cn);
        ATS(&h0n[idx], hv);
        if (t == TT - 1) { p.out_cf[idx] = cn; p.out_hf[idx] = hv; }
      }
    } else {
      const size_t wr = (size_t)(gate * 512 + colj) * 512;
      stageC(p.h1s + rowbase);
      f32x4 acc = gemm_half(p.Whh1 + wr + kq, p.Whh1 + NW1 + wr + kq, zero4());
      const float bb = p.b1[gate * 512 + colj];
#pragma unroll
      for (int r = 0; r < 4; ++r)
        ATS(&p.part1[(g * 16 + (lane >> 4) * 4 + r) * 2048 + gate * 512 + colj],
            acc[r] + bb);
    }
    gbar();

    // ---- P2: gates1(ih part) + part1 + cell1 (u<32); ctx zero (u>=32) ----
    if (u < 32) {
      const size_t wr = (size_t)(gate * 512 + colj) * 512;
      stageC(h0n + rowbase);
      f32x4 acc = gemm_half(p.Wih1 + wr + kq, p.Wih1 + NW1 + wr + kq, zero4());
#pragma unroll
      for (int r = 0; r < 4; ++r) {
        acc[r] += ATL(&p.part1[(g * 16 + (lane >> 4) * 4 + r) * 2048 +
                               gate * 512 + colj]);
        exch[gate][(lane >> 4) * 4 + r][arow] = acc[r];
      }
      __syncthreads();
      {
        int br = tid >> 4, nc = tid & 15;
        int idx = rowbase + br * 512 + strip * 16 + nc;
        float iv = sigm(exch[0][br][nc]);
        float fv = sigm(exch[1][br][nc]);
        float gv = tanhf(exch[2][br][nc]);
        float ov = sigm(exch[3][br][nc]);
        float cn = fv * p.c1s[idx] + iv * gv;
        p.c1s[idx] = cn;
        float hv = ov * tanhf(cn);
        ATS(&p.h1s[idx], hv);
        if (t == TT - 1) { p.out_cf[BB * HH + idx] = cn; p.out_hf[BB * HH + idx] = hv; }
      }
    } else {
      int base = g * 8192 + (u - 32) * 256 + tid;
      ATS(&p.ctx[base], 0.f);
    }
    gbar();

    // ---- P3: attention (4 WGs per batch; scores from LDS Mw, ctx from f32 mbank) ----
    {
      float h8[8];
      {
        const float* hp = p.h1s + attb * 512 + lane * 8;
        float4 a, c;
        asm volatile("global_load_dwordx4 %0, %1, off sc0 sc1" : "=v"(a) : "v"(hp));
        asm volatile("global_load_dwordx4 %0, %1, off sc0 sc1" : "=v"(c) : "v"(hp + 4));
        asm volatile("s_waitcnt vmcnt(0)" ::: "memory");
        __builtin_amdgcn_sched_barrier(0);
        h8[0] = a.x; h8[1] = a.y; h8[2] = a.z; h8[3] = a.w;
        h8[4] = c.x; h8[5] = c.y; h8[6] = c.z; h8[7] = c.w;
      }
#pragma unroll
      for (int i = 0; i < 8; ++i) {
        const int sl = wave * 8 + i;
        const float* mw = &MwL[sl][lane * 8];
        float d = h8[0] * mw[0] + h8[1] * mw[1] + h8[2] * mw[2] + h8[3] * mw[3] +
                  h8[4] * mw[4] + h8[5] * mw[5] + h8[6] * mw[6] + h8[7] * mw[7];
#pragma unroll
        for (int o = 32; o; o >>= 1) d += __shfl_xor(d, o);
        if (lane == 0) ATS(&p.scg[attb * 128 + attq * 32 + sl], d);
      }
      asm volatile("s_waitcnt vmcnt(0)" ::: "memory");
      __syncthreads();                   // all score stores drained
      if (tid == 0) {
        ATA(&p.flag[attb], 1u);
        const unsigned tgt = 4u * (unsigned)(t + 1);
        while (ATL(&p.flag[attb]) < tgt) __builtin_amdgcn_s_sleep(1);
      }
      __syncthreads();
      if (tid < 128) scl[tid] = ATL(&p.scg[attb * 128 + tid]);
      __syncthreads();
      if (wave == 0) {
        const int lenb = p.len[attb];
        float s0 = (lane < lenb) ? scl[lane] : -__builtin_inff();
        float s1 = (lane + 64 < lenb) ? scl[lane + 64] : -__builtin_inff();
        float mx = fmaxf(s0, s1);
#pragma unroll
        for (int o = 32; o; o >>= 1) mx = fmaxf(mx, __shfl_xor(mx, o));
        float e0 = (lane < lenb) ? __expf(s0 - mx) : 0.f;
        float e1 = (lane + 64 < lenb) ? __expf(s1 - mx) : 0.f;
        float sm = e0 + e1;
#pragma unroll
        for (int o = 32; o; o >>= 1) sm += __shfl_xor(sm, o);
        float inv = 1.f / sm;
        pl[lane] = e0 * inv; pl[lane + 64] = e1 * inv;
        if (attq == 0) {
          float* ao = p.out_attn + ((size_t)t * BB + attb) * SS;
          ao[lane] = e0 * inv; ao[lane + 64] = e1 * inv;
        }
      }
      __syncthreads();
      {
        const float* MbB = p.mbank + (size_t)(attb * 128 + attq * 32) * 512;
        const int h2 = tid * 2;
        float ca = 0.f, cb = 0.f;
#pragma unroll 4
        for (int s = 0; s < 32; ++s) {
          float ps = pl[attq * 32 + s];
          float2 v = *(const float2*)(MbB + (size_t)s * 512 + h2);
          ca += ps * v.x;
          cb += ps * v.y;
        }
        atomicAdd(&p.ctx[attb * 512 + h2], ca);
        atomicAdd(&p.ctx[attb * 512 + h2 + 1], cb);
      }
    }
    gbar();

    // ---- P4: attn_h = tanh([ctx | h1] @ Wout^T) -> out_dec, feed (u<8) ----
    if (u < 8) {
      const int nstrip = u * 4 + wave;
      const int cj = nstrip * 16 + arow;
      const size_t wr = (size_t)cj * 1024;
      f32x4 acc = zero4();
      stageC(p.ctx + rowbase);
      acc = gemm_half(p.Wout + wr + kq, p.Wout + NWO + wr + kq, acc);
      stageC(p.h1s + rowbase);
      acc = gemm_half(p.Wout + wr + 512 + kq, p.Wout + NWO + wr + 512 + kq, acc);
      float* dec = p.out_dec + (size_t)t * BB * HH;
#pragma unroll
      for (int r = 0; r < 4; ++r) {
        int b = g * 16 + (lane >> 4) * 4 + r;
        float v = tanhf(acc[r]);
        dec[b * 512 + cj] = v;
        ATS(&p.feed[b * 512 + cj], v);
      }
    }
    gbar();
  }
}

extern "C" void kernel_launch(void* const* d_in, const int* in_sizes, int n_in,
                              void* d_out, int out_size, void* d_ws, size_t ws_size,
                              hipStream_t stream) {
  P p;
  p.tok   = (const int*)d_in[0];
  p.mbank = (const float*)d_in[1];
  p.len   = (const int*)d_in[2];
  p.h0_in = (const float*)d_in[3];
  p.c0_in = (const float*)d_in[4];
  p.emb   = (const float*)d_in[5];
  p.w_ih0 = (const float*)d_in[6];
  p.w_hh0 = (const float*)d_in[7];
  p.b_ih0 = (const float*)d_in[8];
  p.b_hh0 = (const float*)d_in[9];
  p.w_ih1 = (const float*)d_in[10];
  p.w_hh1 = (const float*)d_in[11];
  p.b_ih1 = (const float*)d_in[12];
  p.b_hh1 = (const float*)d_in[13];
  p.w_in  = (const float*)d_in[14];
  p.w_out = (const float*)d_in[15];

  float* out = (float*)d_out;
  p.out_dec  = out;
  p.out_attn = out + (size_t)TT * BB * HH;
  p.out_hf   = out + (size_t)TT * BB * HH + (size_t)TT * BB * SS;
  p.out_cf   = p.out_hf + 2 * BB * HH;

  char* w = (char*)d_ws;
  auto alloc = [&](size_t n) { char* r = w; w += (n + 255) & ~(size_t)255; return r; };
  p.W0E   = (unsigned short*)alloc((size_t)NW0E * 2 * 2);
  p.W0R   = (unsigned short*)alloc((size_t)NW0R * 2 * 2);
  p.Wih1  = (unsigned short*)alloc((size_t)NW1 * 2 * 2);
  p.Whh1  = (unsigned short*)alloc((size_t)NW1 * 2 * 2);
  p.Wout  = (unsigned short*)alloc((size_t)NWO * 2 * 2);
  p.WinT  = (unsigned short*)alloc((size_t)NWI * 2 * 2);
  p.EGb   = (float*)alloc((size_t)4096 * 2048 * 4);
  p.Mw    = (float*)alloc((size_t)BB * SS * HH * 4);
  p.b0    = (float*)alloc(2048 * 4);
  p.b1    = (float*)alloc(2048 * 4);
  p.h0buf = (float*)alloc((size_t)2 * BB * HH * 4);
  p.h1s   = (float*)alloc((size_t)BB * HH * 4);
  p.c0s   = (float*)alloc((size_t)BB * HH * 4);
  p.c1s   = (float*)alloc((size_t)BB * HH * 4);
  p.feed  = (float*)alloc((size_t)BB * HH * 4);
  p.part1 = (float*)alloc((size_t)BB * GG * 4);
  p.ctx   = (float*)alloc((size_t)BB * HH * 4);
  p.scg   = (float*)alloc((size_t)BB * SS * 4);
  p.flag  = (unsigned int*)alloc(1024 * 4);

  hipLaunchKernelGGL(prep_weights, dim3(4096), dim3(256), 0, stream, p);
  hipLaunchKernelGGL(prep_mw, dim3(4096), dim3(256), 0, stream, p);
  hipLaunchKernelGGL(prep_eg, dim3(8192), dim3(256), 0, stream, p);
  void* args[] = {(void*)&p};
  hipLaunchCooperativeKernel((void*)decoder_main, dim3(256), dim3(256), args, 0, stream);
}